// Round 1
// baseline (1352.888 us; speedup 1.0000x reference)
//
#include <hip/hip_runtime.h>
#include <stdint.h>
#include <math.h>

// ---------------------------------------------------------------------------
// PAAE layer, MI355X (gfx950). Round 1: correctness-first full pipeline.
//   - big GEMMs: m97-style 128x128x32 bf16 MFMA + global_load_lds(16B)
//   - skinny N=64 GEMMs: 64x64x32 MFMA, staged-converted from fp32
//   - a-matrix computed transposed (aT = tanh(aw @ h^T + ab)) so every GEMM
//     sees row-major [rows, K] operands (B^T form) and coalesced stores.
// ---------------------------------------------------------------------------

typedef short short8 __attribute__((ext_vector_type(8)));     // 8 x bf16 bits
typedef unsigned short ushort8 __attribute__((ext_vector_type(8)));
typedef float f32x4 __attribute__((ext_vector_type(4)));

#define DEVI static __device__ __forceinline__

DEVI unsigned short f2bf(float f) {  // RNE float -> bf16 bits
  uint32_t u = __builtin_bit_cast(uint32_t, f);
  return (unsigned short)((u + 0x7fffu + ((u >> 16) & 1u)) >> 16);
}
DEVI float bf2f(unsigned short h) {
  return __builtin_bit_cast(float, (uint32_t)h << 16);
}
DEVI float sigmoidf_(float x) { return 1.0f / (1.0f + expf(-x)); }

// async global->LDS, 16 bytes per lane (wave-uniform LDS base + lane*16)
DEVI void gld16(const void* g, void* l) {
  __builtin_amdgcn_global_load_lds(
      (const __attribute__((address_space(1))) unsigned int*)g,
      (__attribute__((address_space(3))) unsigned int*)l, 16, 0, 0);
}

// ---------------------------------------------------------------------------
// fp32 -> bf16 convert (grid-stride, 8 elem/thread)
// ---------------------------------------------------------------------------
__global__ __launch_bounds__(256) void k_f32_to_bf16(
    const float* __restrict__ s, unsigned short* __restrict__ d, long n) {
  long i0 = ((long)blockIdx.x * 256 + threadIdx.x) * 8;
  long stride = (long)gridDim.x * 256 * 8;
  for (long i = i0; i < n; i += stride) {
    f32x4 a = *(const f32x4*)(s + i);
    f32x4 b = *(const f32x4*)(s + i + 4);
    ushort8 o;
    o[0] = f2bf(a[0]); o[1] = f2bf(a[1]); o[2] = f2bf(a[2]); o[3] = f2bf(a[3]);
    o[4] = f2bf(b[0]); o[5] = f2bf(b[1]); o[6] = f2bf(b[2]); o[7] = f2bf(b[3]);
    *(ushort8*)(d + i) = o;
  }
}

// ---------------------------------------------------------------------------
// 128x128 bf16 MFMA GEMM:  C[M,N] = A[M,K] * B[N,K]^T   (both row-major, K-contig)
// EPI 0: outF = acc (f32)
// EPI 1: outB = bf16(tanh(acc + bias[row]))     (aT = tanh(aw.h^T + ab))
// EPI 2: outB = bf16(tanh(relu(acc + bias[col])))   (h = tanh(relu(x.mw^T+mb)))
// Requires M%128==0, N%128==0, K%32==0.
// ---------------------------------------------------------------------------
template <int EPI>
__global__ __launch_bounds__(256) void k_gemm128(
    const unsigned short* __restrict__ A, const unsigned short* __restrict__ B,
    float* __restrict__ outF, unsigned short* __restrict__ outB,
    const float* __restrict__ bias, int M, int N, int K) {
  __shared__ unsigned short As[128 * 32];
  __shared__ unsigned short Bs[128 * 32];
  const int tid = threadIdx.x, lane = tid & 63, wid = tid >> 6;
  const int wr = wid >> 1, wc = wid & 1;
  const int bm = blockIdx.x * 128, bn = blockIdx.y * 128;
  const int c0 = tid, c1 = tid + 256;  // 16B chunks: 512 per 8KB tile

  f32x4 acc[4][4] = {};

  for (int k0 = 0; k0 < K; k0 += 32) {
    gld16(A + (size_t)(bm + (c0 >> 2)) * K + k0 + ((c0 & 3) << 3), As + c0 * 8);
    gld16(A + (size_t)(bm + (c1 >> 2)) * K + k0 + ((c1 & 3) << 3), As + c1 * 8);
    gld16(B + (size_t)(bn + (c0 >> 2)) * K + k0 + ((c0 & 3) << 3), Bs + c0 * 8);
    gld16(B + (size_t)(bn + (c1 >> 2)) * K + k0 + ((c1 & 3) << 3), Bs + c1 * 8);
    __syncthreads();  // compiler emits vmcnt(0) drain before barrier

    short8 af[4], bfr[4];
    const int kr = (lane >> 4) << 3;
#pragma unroll
    for (int mi = 0; mi < 4; mi++)
      af[mi] = *(const short8*)(As + (wr * 64 + mi * 16 + (lane & 15)) * 32 + kr);
#pragma unroll
    for (int ni = 0; ni < 4; ni++)
      bfr[ni] = *(const short8*)(Bs + (wc * 64 + ni * 16 + (lane & 15)) * 32 + kr);
#pragma unroll
    for (int mi = 0; mi < 4; mi++)
#pragma unroll
      for (int ni = 0; ni < 4; ni++)
        acc[mi][ni] = __builtin_amdgcn_mfma_f32_16x16x32_bf16(
            af[mi], bfr[ni], acc[mi][ni], 0, 0, 0);
    __syncthreads();
  }

#pragma unroll
  for (int mi = 0; mi < 4; mi++) {
#pragma unroll
    for (int ni = 0; ni < 4; ni++) {
      const int col = bn + wc * 64 + ni * 16 + (lane & 15);
#pragma unroll
      for (int r = 0; r < 4; r++) {
        const int row = bm + wr * 64 + mi * 16 + ((lane >> 4) << 2) + r;
        const float v = acc[mi][ni][r];
        if (EPI == 0) {
          outF[(size_t)row * N + col] = v;
        } else if (EPI == 1) {
          outB[(size_t)row * N + col] = f2bf(tanhf(v + bias[row]));
        } else {
          outB[(size_t)row * N + col] = f2bf(tanhf(fmaxf(v + bias[col], 0.0f)));
        }
      }
    }
  }
}

// ---------------------------------------------------------------------------
// Skinny GEMM, N = 64:  C[M,64] = A[M,K] * B[64,K]^T
// AMODE 0: A fp32 row-major (lda)   1: A = fp32 src transposed (A[m,k]=src[k*lda+m])
// AMODE 2: A bf16 row-major (lda)
// BMODE 0: B fp32 [64,K]            2: B bf16 [64,K]
// Outputs (any may be null): oF f32 [M,64]; oB bf16 [M,64]; oT bf16 [64,ldT] (transposed)
// Two problem instances selected by blockIdx.y (branch batching).
// ---------------------------------------------------------------------------
template <int AMODE, int BMODE>
__global__ __launch_bounds__(256) void k_sgemm64(
    const void* __restrict__ A0, const void* __restrict__ A1,
    const void* __restrict__ B0, const void* __restrict__ B1,
    float* oF0, float* oF1, unsigned short* oB0, unsigned short* oB1,
    unsigned short* oT0, unsigned short* oT1, int K, int lda, int ldT) {
  const int br = blockIdx.y;
  const void* Av = br ? A1 : A0;
  const void* Bv = br ? B1 : B0;
  float* oF = br ? oF1 : oF0;
  unsigned short* oB = br ? oB1 : oB0;
  unsigned short* oT = br ? oT1 : oT0;

  __shared__ unsigned short As[64 * 40];  // +8 bf16 pad keeps 16B alignment
  __shared__ unsigned short Bs[64 * 40];
  const int tid = threadIdx.x, lane = tid & 63, w = tid >> 6;
  const int tm = blockIdx.x * 64;

  f32x4 acc[4] = {};

  for (int k0 = 0; k0 < K; k0 += 32) {
    if (AMODE == 0) {
      const float* Af = (const float*)Av;
      const int m = tid >> 2, k8 = (tid & 3) << 3;
      f32x4 x0 = *(const f32x4*)(Af + (size_t)(tm + m) * lda + k0 + k8);
      f32x4 x1 = *(const f32x4*)(Af + (size_t)(tm + m) * lda + k0 + k8 + 4);
      ushort8 o;
      o[0] = f2bf(x0[0]); o[1] = f2bf(x0[1]); o[2] = f2bf(x0[2]); o[3] = f2bf(x0[3]);
      o[4] = f2bf(x1[0]); o[5] = f2bf(x1[1]); o[6] = f2bf(x1[2]); o[7] = f2bf(x1[3]);
      *(ushort8*)(As + m * 40 + k8) = o;
    } else if (AMODE == 1) {
      const float* Af = (const float*)Av;
#pragma unroll
      for (int t = 0; t < 2; t++) {
        const int c = tid + t * 256;
        const int u = c >> 4, i4 = (c & 15) << 2;
        f32x4 x = *(const f32x4*)(Af + (size_t)(k0 + u) * lda + tm + i4);
        As[(i4 + 0) * 40 + u] = f2bf(x[0]);
        As[(i4 + 1) * 40 + u] = f2bf(x[1]);
        As[(i4 + 2) * 40 + u] = f2bf(x[2]);
        As[(i4 + 3) * 40 + u] = f2bf(x[3]);
      }
    } else {
      const unsigned short* Ab = (const unsigned short*)Av;
      const int m = tid >> 2, k8 = (tid & 3) << 3;
      *(ushort8*)(As + m * 40 + k8) =
          *(const ushort8*)(Ab + (size_t)(tm + m) * lda + k0 + k8);
    }
    if (BMODE == 0) {
      const float* Bf = (const float*)Bv;
      const int n = tid >> 2, k8 = (tid & 3) << 3;
      f32x4 x0 = *(const f32x4*)(Bf + (size_t)n * K + k0 + k8);
      f32x4 x1 = *(const f32x4*)(Bf + (size_t)n * K + k0 + k8 + 4);
      ushort8 o;
      o[0] = f2bf(x0[0]); o[1] = f2bf(x0[1]); o[2] = f2bf(x0[2]); o[3] = f2bf(x0[3]);
      o[4] = f2bf(x1[0]); o[5] = f2bf(x1[1]); o[6] = f2bf(x1[2]); o[7] = f2bf(x1[3]);
      *(ushort8*)(Bs + n * 40 + k8) = o;
    } else {
      const unsigned short* Bb = (const unsigned short*)Bv;
      const int n = tid >> 2, k8 = (tid & 3) << 3;
      *(ushort8*)(Bs + n * 40 + k8) =
          *(const ushort8*)(Bb + (size_t)n * K + k0 + k8);
    }
    __syncthreads();

    const int kr = (lane >> 4) << 3;
    short8 a = *(const short8*)(As + (w * 16 + (lane & 15)) * 40 + kr);
#pragma unroll
    for (int ni = 0; ni < 4; ni++) {
      short8 bb = *(const short8*)(Bs + (ni * 16 + (lane & 15)) * 40 + kr);
      acc[ni] = __builtin_amdgcn_mfma_f32_16x16x32_bf16(a, bb, acc[ni], 0, 0, 0);
    }
    __syncthreads();
  }

#pragma unroll
  for (int ni = 0; ni < 4; ni++) {
    const int col = ni * 16 + (lane & 15);
#pragma unroll
    for (int r = 0; r < 4; r++) {
      const int row = tm + w * 16 + ((lane >> 4) << 2) + r;
      const float v = acc[ni][r];
      if (oF) oF[(size_t)row * 64 + col] = v;
      if (oB) oB[(size_t)row * 64 + col] = f2bf(v);
      if (oT) oT[(size_t)col * ldT + row] = f2bf(v);
    }
  }
}

// ---------------------------------------------------------------------------
// Row softmax: scores f32 [2048, 4096] -> at bf16. One block (256t) per row.
// ---------------------------------------------------------------------------
__global__ __launch_bounds__(256) void k_softmax(
    const float* __restrict__ S, unsigned short* __restrict__ P) {
  const int row = blockIdx.x, tid = threadIdx.x;
  const float* s = S + (size_t)row * 4096;
  float v[16];
  float m = -1e30f;
#pragma unroll
  for (int j = 0; j < 16; j++) {
    v[j] = s[tid + j * 256];
    m = fmaxf(m, v[j]);
  }
  __shared__ float red[4], red2[4];
  for (int o = 32; o; o >>= 1) m = fmaxf(m, __shfl_down(m, o));
  if ((tid & 63) == 0) red[tid >> 6] = m;
  __syncthreads();
  m = fmaxf(fmaxf(red[0], red[1]), fmaxf(red[2], red[3]));
  float sum = 0.0f;
#pragma unroll
  for (int j = 0; j < 16; j++) {
    v[j] = expf(v[j] - m);
    sum += v[j];
  }
  for (int o = 32; o; o >>= 1) sum += __shfl_down(sum, o);
  if ((tid & 63) == 0) red2[tid >> 6] = sum;
  __syncthreads();
  const float inv = 1.0f / (red2[0] + red2[1] + red2[2] + red2[3]);
  unsigned short* p = P + (size_t)row * 4096;
#pragma unroll
  for (int j = 0; j < 16; j++) p[tid + j * 256] = f2bf(v[j] * inv);
}

// ---------------------------------------------------------------------------
// Final user path: u_b = sigmoid([ue_b|ue_at_b] @ mlp_w^T + mlp_b),
// fusion = rate*u_mp + (1-rate)*u_pmp, out = tanh(fusion @ tr_w^T + tr_b).
// One wave per user row; lane = output dim d.
// ---------------------------------------------------------------------------
__global__ __launch_bounds__(256) void k_user(
    const float* __restrict__ ue_mp, const float* __restrict__ ueat_mp,
    const float* __restrict__ ue_pmp, const float* __restrict__ ueat_pmp,
    const float* __restrict__ mlp_w, const float* __restrict__ mlp_b,
    const float* __restrict__ tr_w, const float* __restrict__ tr_b,
    float* __restrict__ out) {
  const int tid = threadIdx.x, d = tid & 63, w = tid >> 6;
  const int m = blockIdx.x * 4 + w;
  __shared__ float fus[4][64];
  float a1 = mlp_b[d], a2 = a1;
  const float* r1 = ue_mp + (size_t)m * 64;
  const float* r2 = ueat_mp + (size_t)m * 64;
  const float* r3 = ue_pmp + (size_t)m * 64;
  const float* r4 = ueat_pmp + (size_t)m * 64;
  const float* w1 = mlp_w + (size_t)d * 128;
#pragma unroll 8
  for (int k = 0; k < 64; k++) {
    const float wv = w1[k];
    a1 += r1[k] * wv;
    a2 += r3[k] * wv;
  }
#pragma unroll 8
  for (int k = 0; k < 64; k++) {
    const float wv = w1[64 + k];
    a1 += r2[k] * wv;
    a2 += r4[k] * wv;
  }
  const float u1 = sigmoidf_(a1), u2 = sigmoidf_(a2);
  const float rate = sigmoidf_(u1 + u2);
  fus[w][d] = rate * u1 + (1.0f - rate) * u2;
  __syncthreads();
  float o = tr_b[d];
  const float* tw = tr_w + (size_t)d * 64;
#pragma unroll 8
  for (int k = 0; k < 64; k++) o += fus[w][k] * tw[k];
  out[(size_t)m * 64 + d] = tanhf(o);
}

// ---------------------------------------------------------------------------
// item_embeddings = sigmoid([ie_mp|ie_pmp] @ mlp_w^T + mlp_b)
// ---------------------------------------------------------------------------
__global__ __launch_bounds__(256) void k_item(
    const float* __restrict__ ie_mp, const float* __restrict__ ie_pmp,
    const float* __restrict__ mlp_w, const float* __restrict__ mlp_b,
    float* __restrict__ out) {
  const int tid = threadIdx.x, d = tid & 63, w = tid >> 6;
  const int i = blockIdx.x * 4 + w;
  float a = mlp_b[d];
  const float* r1 = ie_mp + (size_t)i * 64;
  const float* r2 = ie_pmp + (size_t)i * 64;
  const float* wp = mlp_w + (size_t)d * 128;
#pragma unroll 8
  for (int k = 0; k < 64; k++) {
    a += r1[k] * wp[k];
    a += r2[k] * wp[64 + k];
  }
  out[(size_t)i * 64 + d] = sigmoidf_(a);
}

// ---------------------------------------------------------------------------
extern "C" void kernel_launch(void* const* d_in, const int* in_sizes, int n_in,
                              void* d_out, int out_size, void* d_ws,
                              size_t ws_size, hipStream_t stream) {
  const int U = 2048, I = 4096, D = 64, UI = 6144;

  const float* ui[2] = {(const float*)d_in[0], (const float*)d_in[1]};
  const float* Wu[2] = {(const float*)d_in[2], (const float*)d_in[3]};
  const float* Wi[2] = {(const float*)d_in[4], (const float*)d_in[5]};
  const float* mw[2] = {(const float*)d_in[6], (const float*)d_in[11]};
  const float* mb[2] = {(const float*)d_in[7], (const float*)d_in[12]};
  const float* aw[2] = {(const float*)d_in[8], (const float*)d_in[13]};
  const float* ab[2] = {(const float*)d_in[9], (const float*)d_in[14]};
  const float* Wat[2] = {(const float*)d_in[10], (const float*)d_in[15]};
  const float* mlp_w = (const float*)d_in[16];
  const float* mlp_b = (const float*)d_in[17];
  const float* tr_w = (const float*)d_in[18];
  const float* tr_b = (const float*)d_in[19];

  char* ws = (char*)d_ws;
  size_t off = 0;
  auto alloc = [&](size_t bytes) {
    void* p = ws + off;
    off += (bytes + 255) & ~(size_t)255;
    return p;
  };
  // shared (reused across branches)
  unsigned short* aw_bf = (unsigned short*)alloc((size_t)I * I * 2);
  unsigned short* Wat_bf = (unsigned short*)alloc((size_t)U * UI * 2);
  unsigned short* mw_bf = (unsigned short*)alloc((size_t)I * D * 2);
  unsigned short* h_bf = (unsigned short*)alloc((size_t)UI * I * 2);
  unsigned short* aT_bf = (unsigned short*)alloc((size_t)I * UI * 2);
  float* scores = (float*)alloc((size_t)U * I * 4);
  unsigned short* at_bf = (unsigned short*)alloc((size_t)U * I * 2);
  // per-branch
  unsigned short* x_bf[2];
  float* ue_f[2];
  float* ie_f[2];
  unsigned short* ieT[2];
  float* ueat_f[2];
  for (int b = 0; b < 2; b++) {
    x_bf[b] = (unsigned short*)alloc((size_t)UI * D * 2);
    ue_f[b] = (float*)alloc((size_t)U * D * 4);
    ie_f[b] = (float*)alloc((size_t)I * D * 4);
    ieT[b] = (unsigned short*)alloc((size_t)D * I * 2);
    ueat_f[b] = (float*)alloc((size_t)U * D * 4);
  }

  const dim3 blk(256);

  // ue (both branches): A=ui f32 [U,I], B=Wu f32 [D,I] -> ue_f32 + x_bf[0:U]
  k_sgemm64<0, 0><<<dim3(U / 64, 2), blk, 0, stream>>>(
      ui[0], ui[1], Wu[0], Wu[1], ue_f[0], ue_f[1], x_bf[0], x_bf[1], nullptr,
      nullptr, I, I, 0);
  // ie (both branches): A=ui^T, B=Wi f32 [D,U] -> ie_f32 + x_bf[U:] + ieT
  k_sgemm64<1, 0><<<dim3(I / 64, 2), blk, 0, stream>>>(
      ui[0], ui[1], Wi[0], Wi[1], ie_f[0], ie_f[1], x_bf[0] + (size_t)U * D,
      x_bf[1] + (size_t)U * D, ieT[0], ieT[1], U, I, I);

  for (int b = 0; b < 2; b++) {
    k_f32_to_bf16<<<2048, blk, 0, stream>>>(aw[b], aw_bf, (long)I * I);
    k_f32_to_bf16<<<2048, blk, 0, stream>>>(Wat[b], Wat_bf, (long)U * UI);
    k_f32_to_bf16<<<128, blk, 0, stream>>>(mw[b], mw_bf, (long)I * D);

    // h = tanh(relu(x @ mw^T + mb)) : [6144,4096], K=64
    k_gemm128<2><<<dim3(UI / 128, I / 128), blk, 0, stream>>>(
        x_bf[b], mw_bf, nullptr, h_bf, mb[b], UI, I, D);
    // aT = tanh(aw @ h^T + ab) : [4096,6144], K=4096
    k_gemm128<1><<<dim3(I / 128, UI / 128), blk, 0, stream>>>(
        aw_bf, h_bf, nullptr, aT_bf, ab[b], I, UI, I);
    // scores = Wat @ a = Wat[U,UI] * aT[I,UI]^T : [2048,4096], K=6144
    k_gemm128<0><<<dim3(U / 128, I / 128), blk, 0, stream>>>(
        Wat_bf, aT_bf, scores, nullptr, nullptr, U, I, UI);
    // at = softmax rows
    k_softmax<<<U, blk, 0, stream>>>(scores, at_bf);
    // ue_at = at @ ie : A=at bf16 [U,I], B=ieT bf16 [D,I]
    k_sgemm64<2, 2><<<dim3(U / 64, 1), blk, 0, stream>>>(
        at_bf, at_bf, ieT[b], ieT[b], ueat_f[b], ueat_f[b], nullptr, nullptr,
        nullptr, nullptr, I, I, 0);
  }

  float* out_user = (float*)d_out;
  float* out_item = (float*)d_out + (size_t)U * D;
  k_user<<<U / 4, blk, 0, stream>>>(ue_f[0], ueat_f[0], ue_f[1], ueat_f[1],
                                    mlp_w, mlp_b, tr_w, tr_b, out_user);
  k_item<<<I / 4, blk, 0, stream>>>(ie_f[0], ie_f[1], mlp_w, mlp_b, out_item);
}

// Round 2
// 911.366 us; speedup vs baseline: 1.4845x; 1.4845x over previous
//
#include <hip/hip_runtime.h>
#include <stdint.h>
#include <math.h>

// ---------------------------------------------------------------------------
// PAAE layer, MI355X (gfx950). Round 2:
//  - k_gemm256: 256x256xBK64, 8 waves, ring-of-4 k-half LDS slots (128KiB),
//    counted vmcnt(8) pipeline (T3+T4), chunk-XOR LDS swizzle (T2),
//    setprio around MFMA (T5). Used for aT and scores (scores: split-K z=2).
//  - skinny N=64 GEMMs: split-K (KS=8) partials + fused reduce kernels.
// ---------------------------------------------------------------------------

typedef short short8 __attribute__((ext_vector_type(8)));
typedef unsigned short ushort8 __attribute__((ext_vector_type(8)));
typedef float f32x4 __attribute__((ext_vector_type(4)));

#define DEVI static __device__ __forceinline__

DEVI unsigned short f2bf(float f) {  // RNE float -> bf16 bits
  uint32_t u = __builtin_bit_cast(uint32_t, f);
  return (unsigned short)((u + 0x7fffu + ((u >> 16) & 1u)) >> 16);
}
DEVI float sigmoidf_(float x) { return 1.0f / (1.0f + expf(-x)); }

DEVI void gld16(const void* g, void* l) {
  __builtin_amdgcn_global_load_lds(
      (const __attribute__((address_space(1))) unsigned int*)g,
      (__attribute__((address_space(3))) unsigned int*)l, 16, 0, 0);
}

// ---------------------------------------------------------------------------
__global__ __launch_bounds__(256) void k_f32_to_bf16(
    const float* __restrict__ s, unsigned short* __restrict__ d, long n) {
  long i0 = ((long)blockIdx.x * 256 + threadIdx.x) * 8;
  long stride = (long)gridDim.x * 256 * 8;
  for (long i = i0; i < n; i += stride) {
    f32x4 a = *(const f32x4*)(s + i);
    f32x4 b = *(const f32x4*)(s + i + 4);
    ushort8 o;
    o[0] = f2bf(a[0]); o[1] = f2bf(a[1]); o[2] = f2bf(a[2]); o[3] = f2bf(a[3]);
    o[4] = f2bf(b[0]); o[5] = f2bf(b[1]); o[6] = f2bf(b[2]); o[7] = f2bf(b[3]);
    *(ushort8*)(d + i) = o;
  }
}

// ---------------------------------------------------------------------------
// 256x256 deep-pipelined bf16 GEMM: C[M,N] = A[M,K] * B[N,K]^T.
// Ring of 4 k-half slots per operand: slot = [256 rows][32 k] bf16 (16KB).
// Phase g consumes half j=g (tile g>>1, k-half g&1) and stages half g+3.
// vmcnt(8) = 2 halves (8 loads) allowed outstanding -> half g complete.
// LDS swizzle: 16B-chunk index q ^= (row&3); staged via inverse-swizzled
// global source (linear LDS dest for global_load_lds), read with same XOR.
// EPI 0: outF[z*M*N + ...] = acc   (split-K partial, z = blockIdx.z)
// EPI 1: outB = bf16(tanh(acc + bias[row]))
// ---------------------------------------------------------------------------
template <int EPI>
__global__ __launch_bounds__(512, 2) void k_gemm256(
    const unsigned short* __restrict__ A, const unsigned short* __restrict__ B,
    float* __restrict__ outF, unsigned short* __restrict__ outB,
    const float* __restrict__ bias, int M, int N, int K, int kchunk,
    long zsf) {
  __shared__ unsigned short lds[65536];  // A slots [4][256][32] @0; B @32768
  const int tid = threadIdx.x, lane = tid & 63;
  const int wid = tid >> 6, wr = wid >> 2, wc = wid & 3;
  const int bm = blockIdx.x * 256, bn = blockIdx.y * 256;
  const int kz = blockIdx.z;
  const long kbase = (long)kz * kchunk;
  const int NPH = (kchunk / 64) * 2;

  const int R0 = tid >> 2, Q = tid & 3;       // staging row/chunk
  const int q = lane >> 4, rl = lane & 15;    // frag k-quarter / row-in-frag
  const int qe = (q ^ (rl & 3)) << 3;         // swizzled read chunk (shorts)

  f32x4 acc[8][4] = {};

  auto stage = [&](int j) {
    const int slot = j & 3;
    const long kcol = kbase + (long)(j >> 1) * 64 + (j & 1) * 32;
#pragma unroll
    for (int i = 0; i < 2; i++) {
      const int R = i * 128 + R0;
      const int qd = Q ^ (R & 3);  // inverse-swizzle the global source
      gld16(A + (size_t)(bm + R) * K + kcol + qd * 8,
            &lds[slot * 8192 + R * 32 + Q * 8]);
      gld16(B + (size_t)(bn + R) * K + kcol + qd * 8,
            &lds[32768 + slot * 8192 + R * 32 + Q * 8]);
    }
  };

  for (int j = 0; j < 3 && j < NPH; ++j) stage(j);

  for (int g = 0; g < NPH; ++g) {
    // own staging loads for half g drained + barrier => all waves' writes
    // for half g visible; also, all waves finished reading slot (g-1)%4.
    if (g + 2 < NPH)
      asm volatile("s_waitcnt vmcnt(8)\n\ts_barrier" ::: "memory");
    else if (g + 1 < NPH)
      asm volatile("s_waitcnt vmcnt(4)\n\ts_barrier" ::: "memory");
    else
      asm volatile("s_waitcnt vmcnt(0)\n\ts_barrier" ::: "memory");

    const unsigned short* As = &lds[(g & 3) * 8192];
    const unsigned short* Bs = &lds[32768 + (g & 3) * 8192];
    short8 af[8], bfr[4];
#pragma unroll
    for (int m = 0; m < 8; m++)
      af[m] = *(const short8*)(As + (wr * 128 + m * 16 + rl) * 32 + qe);
#pragma unroll
    for (int n = 0; n < 4; n++)
      bfr[n] = *(const short8*)(Bs + (wc * 64 + n * 16 + rl) * 32 + qe);

    if (g + 3 < NPH) stage(g + 3);  // targets slot (g-1)%4, freed last phase

    __builtin_amdgcn_s_setprio(1);
#pragma unroll
    for (int m = 0; m < 8; m++)
#pragma unroll
      for (int n = 0; n < 4; n++)
        acc[m][n] = __builtin_amdgcn_mfma_f32_16x16x32_bf16(af[m], bfr[n],
                                                            acc[m][n], 0, 0, 0);
    __builtin_amdgcn_s_setprio(0);
  }

#pragma unroll
  for (int m = 0; m < 8; m++) {
#pragma unroll
    for (int n = 0; n < 4; n++) {
      const int col = bn + wc * 64 + n * 16 + rl;
#pragma unroll
      for (int r = 0; r < 4; r++) {
        const int row = bm + wr * 128 + m * 16 + q * 4 + r;
        const float v = acc[m][n][r];
        if (EPI == 0)
          outF[(long)kz * zsf + (size_t)row * N + col] = v;
        else
          outB[(size_t)row * N + col] = f2bf(tanhf(v + bias[row]));
      }
    }
  }
}

// ---------------------------------------------------------------------------
// 128x128 bf16 GEMM (retained for h, K=64):
// EPI 2: outB = bf16(tanh(relu(acc + bias[col])))
// ---------------------------------------------------------------------------
template <int EPI>
__global__ __launch_bounds__(256) void k_gemm128(
    const unsigned short* __restrict__ A, const unsigned short* __restrict__ B,
    float* __restrict__ outF, unsigned short* __restrict__ outB,
    const float* __restrict__ bias, int M, int N, int K) {
  __shared__ unsigned short As[128 * 32];
  __shared__ unsigned short Bs[128 * 32];
  const int tid = threadIdx.x, lane = tid & 63, wid = tid >> 6;
  const int wr = wid >> 1, wc = wid & 1;
  const int bm = blockIdx.x * 128, bn = blockIdx.y * 128;
  const int c0 = tid, c1 = tid + 256;

  f32x4 acc[4][4] = {};

  for (int k0 = 0; k0 < K; k0 += 32) {
    gld16(A + (size_t)(bm + (c0 >> 2)) * K + k0 + ((c0 & 3) << 3), As + c0 * 8);
    gld16(A + (size_t)(bm + (c1 >> 2)) * K + k0 + ((c1 & 3) << 3), As + c1 * 8);
    gld16(B + (size_t)(bn + (c0 >> 2)) * K + k0 + ((c0 & 3) << 3), Bs + c0 * 8);
    gld16(B + (size_t)(bn + (c1 >> 2)) * K + k0 + ((c1 & 3) << 3), Bs + c1 * 8);
    __syncthreads();

    short8 af[4], bfr[4];
    const int kr = (lane >> 4) << 3;
#pragma unroll
    for (int mi = 0; mi < 4; mi++)
      af[mi] = *(const short8*)(As + (wr * 64 + mi * 16 + (lane & 15)) * 32 + kr);
#pragma unroll
    for (int ni = 0; ni < 4; ni++)
      bfr[ni] = *(const short8*)(Bs + (wc * 64 + ni * 16 + (lane & 15)) * 32 + kr);
#pragma unroll
    for (int mi = 0; mi < 4; mi++)
#pragma unroll
      for (int ni = 0; ni < 4; ni++)
        acc[mi][ni] = __builtin_amdgcn_mfma_f32_16x16x32_bf16(
            af[mi], bfr[ni], acc[mi][ni], 0, 0, 0);
    __syncthreads();
  }

#pragma unroll
  for (int mi = 0; mi < 4; mi++) {
#pragma unroll
    for (int ni = 0; ni < 4; ni++) {
      const int col = bn + wc * 64 + ni * 16 + (lane & 15);
#pragma unroll
      for (int r = 0; r < 4; r++) {
        const int row = bm + wr * 64 + mi * 16 + ((lane >> 4) << 2) + r;
        const float v = acc[mi][ni][r];
        if (EPI == 0) {
          outF[(size_t)row * N + col] = v;
        } else if (EPI == 1) {
          outB[(size_t)row * N + col] = f2bf(tanhf(v + bias[row]));
        } else {
          outB[(size_t)row * N + col] = f2bf(tanhf(fmaxf(v + bias[col], 0.0f)));
        }
      }
    }
  }
}

// ---------------------------------------------------------------------------
// Skinny GEMM, N=64, split-K: P[br][kz][M][64] += A-chunk * B-chunk^T.
// AMODE 0: A fp32 row-major (lda); 1: A[m,k]=src[k*lda+m] (fp32 transposed);
// AMODE 2: A bf16 row-major (lda). BMODE 0: B fp32 [64][ldb]; 2: bf16 [64][ldb].
// grid: (M/64, KS, nbr)
// ---------------------------------------------------------------------------
template <int AMODE, int BMODE>
__global__ __launch_bounds__(256) void k_sgemm64s(
    const void* __restrict__ A0, const void* __restrict__ A1,
    const void* __restrict__ B0, const void* __restrict__ B1,
    float* __restrict__ P, int kchunk, int lda, int ldb, int M) {
  const int br = blockIdx.z, kz = blockIdx.y, KS = gridDim.y;
  const void* Av = br ? A1 : A0;
  const void* Bv = br ? B1 : B0;

  __shared__ unsigned short As[64 * 40];
  __shared__ unsigned short Bs[64 * 40];
  const int tid = threadIdx.x, lane = tid & 63, w = tid >> 6;
  const int tm = blockIdx.x * 64;

  f32x4 acc[4] = {};
  const int kbeg = kz * kchunk, kend = kbeg + kchunk;

  for (int k0 = kbeg; k0 < kend; k0 += 32) {
    if (AMODE == 0) {
      const float* Af = (const float*)Av;
      const int m = tid >> 2, k8 = (tid & 3) << 3;
      f32x4 x0 = *(const f32x4*)(Af + (size_t)(tm + m) * lda + k0 + k8);
      f32x4 x1 = *(const f32x4*)(Af + (size_t)(tm + m) * lda + k0 + k8 + 4);
      ushort8 o;
      o[0] = f2bf(x0[0]); o[1] = f2bf(x0[1]); o[2] = f2bf(x0[2]); o[3] = f2bf(x0[3]);
      o[4] = f2bf(x1[0]); o[5] = f2bf(x1[1]); o[6] = f2bf(x1[2]); o[7] = f2bf(x1[3]);
      *(ushort8*)(As + m * 40 + k8) = o;
    } else if (AMODE == 1) {
      const float* Af = (const float*)Av;
#pragma unroll
      for (int t = 0; t < 2; t++) {
        const int c = tid + t * 256;
        const int u = c >> 4, i4 = (c & 15) << 2;
        f32x4 x = *(const f32x4*)(Af + (size_t)(k0 + u) * lda + tm + i4);
        As[(i4 + 0) * 40 + u] = f2bf(x[0]);
        As[(i4 + 1) * 40 + u] = f2bf(x[1]);
        As[(i4 + 2) * 40 + u] = f2bf(x[2]);
        As[(i4 + 3) * 40 + u] = f2bf(x[3]);
      }
    } else {
      const unsigned short* Ab = (const unsigned short*)Av;
      const int m = tid >> 2, k8 = (tid & 3) << 3;
      *(ushort8*)(As + m * 40 + k8) =
          *(const ushort8*)(Ab + (size_t)(tm + m) * lda + k0 + k8);
    }
    if (BMODE == 0) {
      const float* Bf = (const float*)Bv;
      const int n = tid >> 2, k8 = (tid & 3) << 3;
      f32x4 x0 = *(const f32x4*)(Bf + (size_t)n * ldb + k0 + k8);
      f32x4 x1 = *(const f32x4*)(Bf + (size_t)n * ldb + k0 + k8 + 4);
      ushort8 o;
      o[0] = f2bf(x0[0]); o[1] = f2bf(x0[1]); o[2] = f2bf(x0[2]); o[3] = f2bf(x0[3]);
      o[4] = f2bf(x1[0]); o[5] = f2bf(x1[1]); o[6] = f2bf(x1[2]); o[7] = f2bf(x1[3]);
      *(ushort8*)(Bs + n * 40 + k8) = o;
    } else {
      const unsigned short* Bb = (const unsigned short*)Bv;
      const int n = tid >> 2, k8 = (tid & 3) << 3;
      *(ushort8*)(Bs + n * 40 + k8) =
          *(const ushort8*)(Bb + (size_t)n * ldb + k0 + k8);
    }
    __syncthreads();

    const int kr = (lane >> 4) << 3;
    short8 a = *(const short8*)(As + (w * 16 + (lane & 15)) * 40 + kr);
#pragma unroll
    for (int ni = 0; ni < 4; ni++) {
      short8 bb = *(const short8*)(Bs + (ni * 16 + (lane & 15)) * 40 + kr);
      acc[ni] = __builtin_amdgcn_mfma_f32_16x16x32_bf16(a, bb, acc[ni], 0, 0, 0);
    }
    __syncthreads();
  }

  float* out = P + ((size_t)(br * KS + kz) * M) * 64;
#pragma unroll
  for (int ni = 0; ni < 4; ni++) {
    const int col = ni * 16 + (lane & 15);
#pragma unroll
    for (int r = 0; r < 4; r++) {
      const int row = tm + w * 16 + ((lane >> 4) << 2) + r;
      out[(size_t)row * 64 + col] = acc[ni][r];
    }
  }
}

// ---------------------------------------------------------------------------
// Reduce KS split-K partials; optional f32 / bf16 / transposed-bf16 outputs.
// grid: (M*64/256, nbr)
// ---------------------------------------------------------------------------
template <int WF, int WB, int WT>
__global__ __launch_bounds__(256) void k_reduce(
    const float* __restrict__ P, size_t pbr_stride, float* F0, float* F1,
    unsigned short* Bo0, unsigned short* Bo1, unsigned short* T0,
    unsigned short* T1, int M, int KS, int ldT) {
  const int br = blockIdx.y;
  const float* Pp = P + (size_t)br * pbr_stride;
  const size_t i = (size_t)blockIdx.x * 256 + threadIdx.x;
  const size_t n = (size_t)M * 64;
  float s = 0.f;
  for (int k = 0; k < KS; k++) s += Pp[(size_t)k * n + i];
  if (WF) (br ? F1 : F0)[i] = s;
  if (WB) (br ? Bo1 : Bo0)[i] = f2bf(s);
  if (WT) {
    const int row = (int)(i >> 6), col = (int)(i & 63);
    (br ? T1 : T0)[(size_t)col * ldT + row] = f2bf(s);
  }
}

// ---------------------------------------------------------------------------
// Row softmax over S0+S1 (split-K partial sum fused): [2048,4096] -> bf16
// ---------------------------------------------------------------------------
__global__ __launch_bounds__(256) void k_softmax(
    const float* __restrict__ S0, const float* __restrict__ S1,
    unsigned short* __restrict__ Pout) {
  const int row = blockIdx.x, tid = threadIdx.x;
  const float* s0 = S0 + (size_t)row * 4096;
  const float* s1 = S1 + (size_t)row * 4096;
  float v[16];
  float m = -1e30f;
#pragma unroll
  for (int j = 0; j < 16; j++) {
    v[j] = s0[tid + j * 256] + s1[tid + j * 256];
    m = fmaxf(m, v[j]);
  }
  __shared__ float red[4], red2[4];
  for (int o = 32; o; o >>= 1) m = fmaxf(m, __shfl_down(m, o));
  if ((tid & 63) == 0) red[tid >> 6] = m;
  __syncthreads();
  m = fmaxf(fmaxf(red[0], red[1]), fmaxf(red[2], red[3]));
  float sum = 0.0f;
#pragma unroll
  for (int j = 0; j < 16; j++) {
    v[j] = expf(v[j] - m);
    sum += v[j];
  }
  for (int o = 32; o; o >>= 1) sum += __shfl_down(sum, o);
  if ((tid & 63) == 0) red2[tid >> 6] = sum;
  __syncthreads();
  const float inv = 1.0f / (red2[0] + red2[1] + red2[2] + red2[3]);
  unsigned short* p = Pout + (size_t)row * 4096;
#pragma unroll
  for (int j = 0; j < 16; j++) p[tid + j * 256] = f2bf(v[j] * inv);
}

// ---------------------------------------------------------------------------
__global__ __launch_bounds__(256) void k_user(
    const float* __restrict__ ue_mp, const float* __restrict__ ueat_mp,
    const float* __restrict__ ue_pmp, const float* __restrict__ ueat_pmp,
    const float* __restrict__ mlp_w, const float* __restrict__ mlp_b,
    const float* __restrict__ tr_w, const float* __restrict__ tr_b,
    float* __restrict__ out) {
  const int tid = threadIdx.x, d = tid & 63, w = tid >> 6;
  const int m = blockIdx.x * 4 + w;
  __shared__ float fus[4][64];
  float a1 = mlp_b[d], a2 = a1;
  const float* r1 = ue_mp + (size_t)m * 64;
  const float* r2 = ueat_mp + (size_t)m * 64;
  const float* r3 = ue_pmp + (size_t)m * 64;
  const float* r4 = ueat_pmp + (size_t)m * 64;
  const float* w1 = mlp_w + (size_t)d * 128;
#pragma unroll 8
  for (int k = 0; k < 64; k++) {
    const float wv = w1[k];
    a1 += r1[k] * wv;
    a2 += r3[k] * wv;
  }
#pragma unroll 8
  for (int k = 0; k < 64; k++) {
    const float wv = w1[64 + k];
    a1 += r2[k] * wv;
    a2 += r4[k] * wv;
  }
  const float u1 = sigmoidf_(a1), u2 = sigmoidf_(a2);
  const float rate = sigmoidf_(u1 + u2);
  fus[w][d] = rate * u1 + (1.0f - rate) * u2;
  __syncthreads();
  float o = tr_b[d];
  const float* tw = tr_w + (size_t)d * 64;
#pragma unroll 8
  for (int k = 0; k < 64; k++) o += fus[w][k] * tw[k];
  out[(size_t)m * 64 + d] = tanhf(o);
}

__global__ __launch_bounds__(256) void k_item(
    const float* __restrict__ ie_mp, const float* __restrict__ ie_pmp,
    const float* __restrict__ mlp_w, const float* __restrict__ mlp_b,
    float* __restrict__ out) {
  const int tid = threadIdx.x, d = tid & 63, w = tid >> 6;
  const int i = blockIdx.x * 4 + w;
  float a = mlp_b[d];
  const float* r1 = ie_mp + (size_t)i * 64;
  const float* r2 = ie_pmp + (size_t)i * 64;
  const float* wp = mlp_w + (size_t)d * 128;
#pragma unroll 8
  for (int k = 0; k < 64; k++) {
    a += r1[k] * wp[k];
    a += r2[k] * wp[64 + k];
  }
  out[(size_t)i * 64 + d] = sigmoidf_(a);
}

// ---------------------------------------------------------------------------
extern "C" void kernel_launch(void* const* d_in, const int* in_sizes, int n_in,
                              void* d_out, int out_size, void* d_ws,
                              size_t ws_size, hipStream_t stream) {
  const int U = 2048, I = 4096, D = 64, UI = 6144;

  const float* ui[2] = {(const float*)d_in[0], (const float*)d_in[1]};
  const float* Wu[2] = {(const float*)d_in[2], (const float*)d_in[3]};
  const float* Wi[2] = {(const float*)d_in[4], (const float*)d_in[5]};
  const float* mw[2] = {(const float*)d_in[6], (const float*)d_in[11]};
  const float* mb[2] = {(const float*)d_in[7], (const float*)d_in[12]};
  const float* aw[2] = {(const float*)d_in[8], (const float*)d_in[13]};
  const float* ab[2] = {(const float*)d_in[9], (const float*)d_in[14]};
  const float* Wat[2] = {(const float*)d_in[10], (const float*)d_in[15]};
  const float* mlp_w = (const float*)d_in[16];
  const float* mlp_b = (const float*)d_in[17];
  const float* tr_w = (const float*)d_in[18];
  const float* tr_b = (const float*)d_in[19];

  char* ws = (char*)d_ws;
  size_t off = 0;
  auto alloc = [&](size_t bytes) {
    void* p = ws + off;
    off += (bytes + 255) & ~(size_t)255;
    return p;
  };
  unsigned short* aw_bf = (unsigned short*)alloc((size_t)I * I * 2);
  unsigned short* Wat_bf = (unsigned short*)alloc((size_t)U * UI * 2);
  unsigned short* mw_bf = (unsigned short*)alloc((size_t)I * D * 2);
  unsigned short* h_bf = (unsigned short*)alloc((size_t)UI * I * 2);   // 48MB
  unsigned short* aT_bf = (unsigned short*)alloc((size_t)I * UI * 2);  // 48MB
  float* scores = (float*)alloc((size_t)U * I * 4);                    // 32MB
  unsigned short* at_bf = (unsigned short*)alloc((size_t)U * I * 2);
  unsigned short* x_bf[2];
  float* ue_f[2];
  float* ie_f[2];
  unsigned short* ieT[2];
  float* ueat_f[2];
  for (int b = 0; b < 2; b++) {
    x_bf[b] = (unsigned short*)alloc((size_t)UI * D * 2);
    ue_f[b] = (float*)alloc((size_t)U * D * 4);
    ie_f[b] = (float*)alloc((size_t)I * D * 4);
    ieT[b] = (unsigned short*)alloc((size_t)D * I * 2);
    ueat_f[b] = (float*)alloc((size_t)U * D * 4);
  }
  // Lifetime-based aliases (no new ws):
  //  pue (8MB, used before h written)        -> h_bf region
  //  pie (16MB, used before aT written)      -> aT_bf region
  //  pueat (4MB, used after scores consumed) -> scores region
  //  scores slab2 (32MB, written after h consumed) -> h_bf region (offset 8MB
  //  would clash with nothing: pue dead by then; use h_bf base)
  float* pue = (float*)h_bf;
  float* pie = (float*)aT_bf;
  float* pueat = scores;  // clobbers scores AFTER softmax read them
  float* scores2 = (float*)h_bf;  // z=1 slab; h dead once aT is built
  const long zsf = (long)(scores2 - scores);  // float offset slab0 -> slab1

  const dim3 blk(256);

  // ue: [U,64] over K=I, both branches, KS=8
  k_sgemm64s<0, 0><<<dim3(U / 64, 8, 2), blk, 0, stream>>>(
      ui[0], ui[1], Wu[0], Wu[1], pue, I / 8, I, I, U);
  k_reduce<1, 1, 0><<<dim3(U * 64 / 256, 2), blk, 0, stream>>>(
      pue, (size_t)8 * U * 64, ue_f[0], ue_f[1], x_bf[0], x_bf[1], nullptr,
      nullptr, U, 8, 0);
  // ie: [I,64] over K=U (A = ui^T), both branches, KS=8
  k_sgemm64s<1, 0><<<dim3(I / 64, 8, 2), blk, 0, stream>>>(
      ui[0], ui[1], Wi[0], Wi[1], pie, U / 8, I, U, I);
  k_reduce<1, 1, 1><<<dim3(I * 64 / 256, 2), blk, 0, stream>>>(
      pie, (size_t)8 * I * 64, ie_f[0], ie_f[1], x_bf[0] + (size_t)U * D,
      x_bf[1] + (size_t)U * D, ieT[0], ieT[1], I, 8, I);

  for (int b = 0; b < 2; b++) {
    k_f32_to_bf16<<<2048, blk, 0, stream>>>(aw[b], aw_bf, (long)I * I);
    k_f32_to_bf16<<<2048, blk, 0, stream>>>(Wat[b], Wat_bf, (long)U * UI);
    k_f32_to_bf16<<<128, blk, 0, stream>>>(mw[b], mw_bf, (long)I * D);

    // h = tanh(relu(x @ mw^T + mb)) : [6144,4096], K=64
    k_gemm128<2><<<dim3(UI / 128, I / 128), blk, 0, stream>>>(
        x_bf[b], mw_bf, nullptr, h_bf, mb[b], UI, I, D);
    // aT = tanh(aw @ h^T + ab) : [4096,6144], K=4096
    k_gemm256<1><<<dim3(I / 256, UI / 256, 1), dim3(512), 0, stream>>>(
        aw_bf, h_bf, nullptr, aT_bf, ab[b], I, UI, I, I, 0);
    // scores = Wat @ a : [2048,4096], K=6144, split-K z=2
    k_gemm256<0><<<dim3(U / 256, I / 256, 2), dim3(512), 0, stream>>>(
        Wat_bf, aT_bf, scores, nullptr, nullptr, U, I, UI, UI / 2, zsf);
    // softmax over slab0+slab1
    k_softmax<<<U, blk, 0, stream>>>(scores, scores2, at_bf);
    // ue_at = at @ ie : [U,64] over K=I, KS=8 (per branch)
    k_sgemm64s<2, 2><<<dim3(U / 64, 8, 1), blk, 0, stream>>>(
        at_bf, at_bf, ieT[b], ieT[b], pueat, I / 8, I, I, U);
    k_reduce<1, 0, 0><<<dim3(U * 64 / 256, 1), blk, 0, stream>>>(
        pueat, 0, ueat_f[b], ueat_f[b], nullptr, nullptr, nullptr, nullptr, U,
        8, 0);
  }

  float* out_user = (float*)d_out;
  float* out_item = (float*)d_out + (size_t)U * D;
  k_user<<<U / 4, blk, 0, stream>>>(ue_f[0], ueat_f[0], ue_f[1], ueat_f[1],
                                    mlp_w, mlp_b, tr_w, tr_b, out_user);
  k_item<<<I / 4, blk, 0, stream>>>(ie_f[0], ie_f[1], mlp_w, mlp_b, out_item);
}

// Round 3
// 889.406 us; speedup vs baseline: 1.5211x; 1.0247x over previous
//
#include <hip/hip_runtime.h>
#include <stdint.h>
#include <math.h>

// ---------------------------------------------------------------------------
// PAAE layer, MI355X (gfx950). Round 3: fix LDS swizzle axis.
// With [rows][32] bf16 slots the row stride is 64B = 16 banks: even rows use
// banks 0-15, odd rows 16-31. Within an aligned 8-lane group (q fixed,
// rl=8j..8j+7) the 4 even-rl lanes must cover chunk positions {0,1,2,3} once.
// XOR with (rl>>1)&3 achieves that; R2's rl&3 gave {0,2} -> 2-way conflict.
// Applied both-sides (inverse-swizzled global source + swizzled read).
// ---------------------------------------------------------------------------

typedef short short8 __attribute__((ext_vector_type(8)));
typedef unsigned short ushort8 __attribute__((ext_vector_type(8)));
typedef float f32x4 __attribute__((ext_vector_type(4)));

#define DEVI static __device__ __forceinline__

DEVI unsigned short f2bf(float f) {  // RNE float -> bf16 bits
  uint32_t u = __builtin_bit_cast(uint32_t, f);
  return (unsigned short)((u + 0x7fffu + ((u >> 16) & 1u)) >> 16);
}
DEVI float sigmoidf_(float x) { return 1.0f / (1.0f + expf(-x)); }

DEVI void gld16(const void* g, void* l) {
  __builtin_amdgcn_global_load_lds(
      (const __attribute__((address_space(1))) unsigned int*)g,
      (__attribute__((address_space(3))) unsigned int*)l, 16, 0, 0);
}

// ---------------------------------------------------------------------------
__global__ __launch_bounds__(256) void k_f32_to_bf16(
    const float* __restrict__ s, unsigned short* __restrict__ d, long n) {
  long i0 = ((long)blockIdx.x * 256 + threadIdx.x) * 8;
  long stride = (long)gridDim.x * 256 * 8;
  for (long i = i0; i < n; i += stride) {
    f32x4 a = *(const f32x4*)(s + i);
    f32x4 b = *(const f32x4*)(s + i + 4);
    ushort8 o;
    o[0] = f2bf(a[0]); o[1] = f2bf(a[1]); o[2] = f2bf(a[2]); o[3] = f2bf(a[3]);
    o[4] = f2bf(b[0]); o[5] = f2bf(b[1]); o[6] = f2bf(b[2]); o[7] = f2bf(b[3]);
    *(ushort8*)(d + i) = o;
  }
}

// ---------------------------------------------------------------------------
// 256x256 deep-pipelined bf16 GEMM: C[M,N] = A[M,K] * B[N,K]^T.
// Ring of 4 k-half slots per operand (16KB each). Counted vmcnt pipeline.
// EPI 0: outF[z*zsf + ...] = acc   (split-K partial, z = blockIdx.z)
// EPI 1: outB = bf16(tanh(acc + bias[row]))
// ---------------------------------------------------------------------------
template <int EPI>
__global__ __launch_bounds__(512, 2) void k_gemm256(
    const unsigned short* __restrict__ A, const unsigned short* __restrict__ B,
    float* __restrict__ outF, unsigned short* __restrict__ outB,
    const float* __restrict__ bias, int M, int N, int K, int kchunk,
    long zsf) {
  __shared__ unsigned short lds[65536];  // A slots [4][256][32] @0; B @32768
  const int tid = threadIdx.x, lane = tid & 63;
  const int wid = tid >> 6, wr = wid >> 2, wc = wid & 3;
  const int bm = blockIdx.x * 256, bn = blockIdx.y * 256;
  const int kz = blockIdx.z;
  const long kbase = (long)kz * kchunk;
  const int NPH = (kchunk / 64) * 2;

  const int R0 = tid >> 2, Q = tid & 3;       // staging row/chunk
  const int qd = Q ^ ((R0 >> 1) & 3);         // inverse-swizzled source chunk
  const int q = lane >> 4, rl = lane & 15;    // frag k-quarter / row-in-frag
  const int qe = (q ^ ((rl >> 1) & 3)) << 3;  // swizzled read offset (shorts)

  f32x4 acc[8][4] = {};

  auto stage = [&](int j) {
    const int slot = j & 3;
    const long kcol = kbase + (long)(j >> 1) * 64 + (j & 1) * 32;
#pragma unroll
    for (int i = 0; i < 2; i++) {
      const int R = i * 128 + R0;  // (R>>1)&3 == (R0>>1)&3 (i*128 ≡ 0 mod 8)
      gld16(A + (size_t)(bm + R) * K + kcol + qd * 8,
            &lds[slot * 8192 + R * 32 + Q * 8]);
      gld16(B + (size_t)(bn + R) * K + kcol + qd * 8,
            &lds[32768 + slot * 8192 + R * 32 + Q * 8]);
    }
  };

  for (int j = 0; j < 3 && j < NPH; ++j) stage(j);

  for (int g = 0; g < NPH; ++g) {
    // own staging loads for half g drained + barrier => all waves' writes
    // for half g visible; also, all waves finished reading slot (g-1)%4.
    if (g + 2 < NPH)
      asm volatile("s_waitcnt vmcnt(8)\n\ts_barrier" ::: "memory");
    else if (g + 1 < NPH)
      asm volatile("s_waitcnt vmcnt(4)\n\ts_barrier" ::: "memory");
    else
      asm volatile("s_waitcnt vmcnt(0)\n\ts_barrier" ::: "memory");

    const unsigned short* As = &lds[(g & 3) * 8192];
    const unsigned short* Bs = &lds[32768 + (g & 3) * 8192];
    short8 af[8], bfr[4];
#pragma unroll
    for (int m = 0; m < 8; m++)
      af[m] = *(const short8*)(As + (wr * 128 + m * 16 + rl) * 32 + qe);
#pragma unroll
    for (int n = 0; n < 4; n++)
      bfr[n] = *(const short8*)(Bs + (wc * 64 + n * 16 + rl) * 32 + qe);

    if (g + 3 < NPH) stage(g + 3);  // targets slot (g-1)%4, freed last phase

    __builtin_amdgcn_s_setprio(1);
#pragma unroll
    for (int m = 0; m < 8; m++)
#pragma unroll
      for (int n = 0; n < 4; n++)
        acc[m][n] = __builtin_amdgcn_mfma_f32_16x16x32_bf16(af[m], bfr[n],
                                                            acc[m][n], 0, 0, 0);
    __builtin_amdgcn_s_setprio(0);
  }

#pragma unroll
  for (int m = 0; m < 8; m++) {
#pragma unroll
    for (int n = 0; n < 4; n++) {
      const int col = bn + wc * 64 + n * 16 + rl;
#pragma unroll
      for (int r = 0; r < 4; r++) {
        const int row = bm + wr * 128 + m * 16 + q * 4 + r;
        const float v = acc[m][n][r];
        if (EPI == 0)
          outF[(long)kz * zsf + (size_t)row * N + col] = v;
        else
          outB[(size_t)row * N + col] = f2bf(tanhf(v + bias[row]));
      }
    }
  }
}

// ---------------------------------------------------------------------------
// 128x128 bf16 GEMM (for h, K=64), same swizzle applied.
// EPI 2: outB = bf16(tanh(relu(acc + bias[col])))
// ---------------------------------------------------------------------------
template <int EPI>
__global__ __launch_bounds__(256) void k_gemm128(
    const unsigned short* __restrict__ A, const unsigned short* __restrict__ B,
    float* __restrict__ outF, unsigned short* __restrict__ outB,
    const float* __restrict__ bias, int M, int N, int K) {
  __shared__ unsigned short As[128 * 32];
  __shared__ unsigned short Bs[128 * 32];
  const int tid = threadIdx.x, lane = tid & 63, wid = tid >> 6;
  const int wr = wid >> 1, wc = wid & 1;
  const int bm = blockIdx.x * 128, bn = blockIdx.y * 128;
  const int c0 = tid, c1 = tid + 256;
  const int s0 = ((c0 & 3) ^ ((c0 >> 3) & 3)) << 3;  // src col swizzle
  const int s1 = ((c1 & 3) ^ ((c1 >> 3) & 3)) << 3;
  const int rl = lane & 15, q = lane >> 4;
  const int qe = (q ^ ((rl >> 1) & 3)) << 3;

  f32x4 acc[4][4] = {};

  for (int k0 = 0; k0 < K; k0 += 32) {
    gld16(A + (size_t)(bm + (c0 >> 2)) * K + k0 + s0, As + c0 * 8);
    gld16(A + (size_t)(bm + (c1 >> 2)) * K + k0 + s1, As + c1 * 8);
    gld16(B + (size_t)(bn + (c0 >> 2)) * K + k0 + s0, Bs + c0 * 8);
    gld16(B + (size_t)(bn + (c1 >> 2)) * K + k0 + s1, Bs + c1 * 8);
    __syncthreads();

    short8 af[4], bfr[4];
#pragma unroll
    for (int mi = 0; mi < 4; mi++)
      af[mi] = *(const short8*)(As + (wr * 64 + mi * 16 + rl) * 32 + qe);
#pragma unroll
    for (int ni = 0; ni < 4; ni++)
      bfr[ni] = *(const short8*)(Bs + (wc * 64 + ni * 16 + rl) * 32 + qe);
#pragma unroll
    for (int mi = 0; mi < 4; mi++)
#pragma unroll
      for (int ni = 0; ni < 4; ni++)
        acc[mi][ni] = __builtin_amdgcn_mfma_f32_16x16x32_bf16(
            af[mi], bfr[ni], acc[mi][ni], 0, 0, 0);
    __syncthreads();
  }

#pragma unroll
  for (int mi = 0; mi < 4; mi++) {
#pragma unroll
    for (int ni = 0; ni < 4; ni++) {
      const int col = bn + wc * 64 + ni * 16 + rl;
#pragma unroll
      for (int r = 0; r < 4; r++) {
        const int row = bm + wr * 64 + mi * 16 + q * 4 + r;
        const float v = acc[mi][ni][r];
        if (EPI == 0) {
          outF[(size_t)row * N + col] = v;
        } else if (EPI == 1) {
          outB[(size_t)row * N + col] = f2bf(tanhf(v + bias[row]));
        } else {
          outB[(size_t)row * N + col] = f2bf(tanhf(fmaxf(v + bias[col], 0.0f)));
        }
      }
    }
  }
}

// ---------------------------------------------------------------------------
// Skinny GEMM, N=64, split-K: P[br][kz][M][64] += A-chunk * B-chunk^T.
// AMODE 0: A fp32 row-major (lda); 1: A[m,k]=src[k*lda+m] (fp32 transposed);
// AMODE 2: A bf16 row-major (lda). BMODE 0: B fp32 [64][ldb]; 2: bf16 [64][ldb].
// grid: (M/64, KS, nbr)
// ---------------------------------------------------------------------------
template <int AMODE, int BMODE>
__global__ __launch_bounds__(256) void k_sgemm64s(
    const void* __restrict__ A0, const void* __restrict__ A1,
    const void* __restrict__ B0, const void* __restrict__ B1,
    float* __restrict__ P, int kchunk, int lda, int ldb, int M) {
  const int br = blockIdx.z, kz = blockIdx.y, KS = gridDim.y;
  const void* Av = br ? A1 : A0;
  const void* Bv = br ? B1 : B0;

  __shared__ unsigned short As[64 * 40];
  __shared__ unsigned short Bs[64 * 40];
  const int tid = threadIdx.x, lane = tid & 63, w = tid >> 6;
  const int tm = blockIdx.x * 64;

  f32x4 acc[4] = {};
  const int kbeg = kz * kchunk, kend = kbeg + kchunk;

  for (int k0 = kbeg; k0 < kend; k0 += 32) {
    if (AMODE == 0) {
      const float* Af = (const float*)Av;
      const int m = tid >> 2, k8 = (tid & 3) << 3;
      f32x4 x0 = *(const f32x4*)(Af + (size_t)(tm + m) * lda + k0 + k8);
      f32x4 x1 = *(const f32x4*)(Af + (size_t)(tm + m) * lda + k0 + k8 + 4);
      ushort8 o;
      o[0] = f2bf(x0[0]); o[1] = f2bf(x0[1]); o[2] = f2bf(x0[2]); o[3] = f2bf(x0[3]);
      o[4] = f2bf(x1[0]); o[5] = f2bf(x1[1]); o[6] = f2bf(x1[2]); o[7] = f2bf(x1[3]);
      *(ushort8*)(As + m * 40 + k8) = o;
    } else if (AMODE == 1) {
      const float* Af = (const float*)Av;
#pragma unroll
      for (int t = 0; t < 2; t++) {
        const int c = tid + t * 256;
        const int u = c >> 4, i4 = (c & 15) << 2;
        f32x4 x = *(const f32x4*)(Af + (size_t)(k0 + u) * lda + tm + i4);
        As[(i4 + 0) * 40 + u] = f2bf(x[0]);
        As[(i4 + 1) * 40 + u] = f2bf(x[1]);
        As[(i4 + 2) * 40 + u] = f2bf(x[2]);
        As[(i4 + 3) * 40 + u] = f2bf(x[3]);
      }
    } else {
      const unsigned short* Ab = (const unsigned short*)Av;
      const int m = tid >> 2, k8 = (tid & 3) << 3;
      *(ushort8*)(As + m * 40 + k8) =
          *(const ushort8*)(Ab + (size_t)(tm + m) * lda + k0 + k8);
    }
    if (BMODE == 0) {
      const float* Bf = (const float*)Bv;
      const int n = tid >> 2, k8 = (tid & 3) << 3;
      f32x4 x0 = *(const f32x4*)(Bf + (size_t)n * ldb + k0 + k8);
      f32x4 x1 = *(const f32x4*)(Bf + (size_t)n * ldb + k0 + k8 + 4);
      ushort8 o;
      o[0] = f2bf(x0[0]); o[1] = f2bf(x0[1]); o[2] = f2bf(x0[2]); o[3] = f2bf(x0[3]);
      o[4] = f2bf(x1[0]); o[5] = f2bf(x1[1]); o[6] = f2bf(x1[2]); o[7] = f2bf(x1[3]);
      *(ushort8*)(Bs + n * 40 + k8) = o;
    } else {
      const unsigned short* Bb = (const unsigned short*)Bv;
      const int n = tid >> 2, k8 = (tid & 3) << 3;
      *(ushort8*)(Bs + n * 40 + k8) =
          *(const ushort8*)(Bb + (size_t)n * ldb + k0 + k8);
    }
    __syncthreads();

    const int kr = (lane >> 4) << 3;
    short8 a = *(const short8*)(As + (w * 16 + (lane & 15)) * 40 + kr);
#pragma unroll
    for (int ni = 0; ni < 4; ni++) {
      short8 bb = *(const short8*)(Bs + (ni * 16 + (lane & 15)) * 40 + kr);
      acc[ni] = __builtin_amdgcn_mfma_f32_16x16x32_bf16(a, bb, acc[ni], 0, 0, 0);
    }
    __syncthreads();
  }

  float* out = P + ((size_t)(br * KS + kz) * M) * 64;
#pragma unroll
  for (int ni = 0; ni < 4; ni++) {
    const int col = ni * 16 + (lane & 15);
#pragma unroll
    for (int r = 0; r < 4; r++) {
      const int row = tm + w * 16 + ((lane >> 4) << 2) + r;
      out[(size_t)row * 64 + col] = acc[ni][r];
    }
  }
}

// ---------------------------------------------------------------------------
// Reduce KS split-K partials; optional f32 / bf16 / transposed-bf16 outputs.
// grid: (M*64/256, nbr)
// ---------------------------------------------------------------------------
template <int WF, int WB, int WT>
__global__ __launch_bounds__(256) void k_reduce(
    const float* __restrict__ P, size_t pbr_stride, float* F0, float* F1,
    unsigned short* Bo0, unsigned short* Bo1, unsigned short* T0,
    unsigned short* T1, int M, int KS, int ldT) {
  const int br = blockIdx.y;
  const float* Pp = P + (size_t)br * pbr_stride;
  const size_t i = (size_t)blockIdx.x * 256 + threadIdx.x;
  const size_t n = (size_t)M * 64;
  float s = 0.f;
  for (int k = 0; k < KS; k++) s += Pp[(size_t)k * n + i];
  if (WF) (br ? F1 : F0)[i] = s;
  if (WB) (br ? Bo1 : Bo0)[i] = f2bf(s);
  if (WT) {
    const int row = (int)(i >> 6), col = (int)(i & 63);
    (br ? T1 : T0)[(size_t)col * ldT + row] = f2bf(s);
  }
}

// ---------------------------------------------------------------------------
// Row softmax over S0+S1 (split-K partial sum fused): [2048,4096] -> bf16
// ---------------------------------------------------------------------------
__global__ __launch_bounds__(256) void k_softmax(
    const float* __restrict__ S0, const float* __restrict__ S1,
    unsigned short* __restrict__ Pout) {
  const int row = blockIdx.x, tid = threadIdx.x;
  const float* s0 = S0 + (size_t)row * 4096;
  const float* s1 = S1 + (size_t)row * 4096;
  float v[16];
  float m = -1e30f;
#pragma unroll
  for (int j = 0; j < 16; j++) {
    v[j] = s0[tid + j * 256] + s1[tid + j * 256];
    m = fmaxf(m, v[j]);
  }
  __shared__ float red[4], red2[4];
  for (int o = 32; o; o >>= 1) m = fmaxf(m, __shfl_down(m, o));
  if ((tid & 63) == 0) red[tid >> 6] = m;
  __syncthreads();
  m = fmaxf(fmaxf(red[0], red[1]), fmaxf(red[2], red[3]));
  float sum = 0.0f;
#pragma unroll
  for (int j = 0; j < 16; j++) {
    v[j] = expf(v[j] - m);
    sum += v[j];
  }
  for (int o = 32; o; o >>= 1) sum += __shfl_down(sum, o);
  if ((tid & 63) == 0) red2[tid >> 6] = sum;
  __syncthreads();
  const float inv = 1.0f / (red2[0] + red2[1] + red2[2] + red2[3]);
  unsigned short* p = Pout + (size_t)row * 4096;
#pragma unroll
  for (int j = 0; j < 16; j++) p[tid + j * 256] = f2bf(v[j] * inv);
}

// ---------------------------------------------------------------------------
__global__ __launch_bounds__(256) void k_user(
    const float* __restrict__ ue_mp, const float* __restrict__ ueat_mp,
    const float* __restrict__ ue_pmp, const float* __restrict__ ueat_pmp,
    const float* __restrict__ mlp_w, const float* __restrict__ mlp_b,
    const float* __restrict__ tr_w, const float* __restrict__ tr_b,
    float* __restrict__ out) {
  const int tid = threadIdx.x, d = tid & 63, w = tid >> 6;
  const int m = blockIdx.x * 4 + w;
  __shared__ float fus[4][64];
  float a1 = mlp_b[d], a2 = a1;
  const float* r1 = ue_mp + (size_t)m * 64;
  const float* r2 = ueat_mp + (size_t)m * 64;
  const float* r3 = ue_pmp + (size_t)m * 64;
  const float* r4 = ueat_pmp + (size_t)m * 64;
  const float* w1 = mlp_w + (size_t)d * 128;
#pragma unroll 8
  for (int k = 0; k < 64; k++) {
    const float wv = w1[k];
    a1 += r1[k] * wv;
    a2 += r3[k] * wv;
  }
#pragma unroll 8
  for (int k = 0; k < 64; k++) {
    const float wv = w1[64 + k];
    a1 += r2[k] * wv;
    a2 += r4[k] * wv;
  }
  const float u1 = sigmoidf_(a1), u2 = sigmoidf_(a2);
  const float rate = sigmoidf_(u1 + u2);
  fus[w][d] = rate * u1 + (1.0f - rate) * u2;
  __syncthreads();
  float o = tr_b[d];
  const float* tw = tr_w + (size_t)d * 64;
#pragma unroll 8
  for (int k = 0; k < 64; k++) o += fus[w][k] * tw[k];
  out[(size_t)m * 64 + d] = tanhf(o);
}

__global__ __launch_bounds__(256) void k_item(
    const float* __restrict__ ie_mp, const float* __restrict__ ie_pmp,
    const float* __restrict__ mlp_w, const float* __restrict__ mlp_b,
    float* __restrict__ out) {
  const int tid = threadIdx.x, d = tid & 63, w = tid >> 6;
  const int i = blockIdx.x * 4 + w;
  float a = mlp_b[d];
  const float* r1 = ie_mp + (size_t)i * 64;
  const float* r2 = ie_pmp + (size_t)i * 64;
  const float* wp = mlp_w + (size_t)d * 128;
#pragma unroll 8
  for (int k = 0; k < 64; k++) {
    a += r1[k] * wp[k];
    a += r2[k] * wp[64 + k];
  }
  out[(size_t)i * 64 + d] = sigmoidf_(a);
}

// ---------------------------------------------------------------------------
extern "C" void kernel_launch(void* const* d_in, const int* in_sizes, int n_in,
                              void* d_out, int out_size, void* d_ws,
                              size_t ws_size, hipStream_t stream) {
  const int U = 2048, I = 4096, D = 64, UI = 6144;

  const float* ui[2] = {(const float*)d_in[0], (const float*)d_in[1]};
  const float* Wu[2] = {(const float*)d_in[2], (const float*)d_in[3]};
  const float* Wi[2] = {(const float*)d_in[4], (const float*)d_in[5]};
  const float* mw[2] = {(const float*)d_in[6], (const float*)d_in[11]};
  const float* mb[2] = {(const float*)d_in[7], (const float*)d_in[12]};
  const float* aw[2] = {(const float*)d_in[8], (const float*)d_in[13]};
  const float* ab[2] = {(const float*)d_in[9], (const float*)d_in[14]};
  const float* Wat[2] = {(const float*)d_in[10], (const float*)d_in[15]};
  const float* mlp_w = (const float*)d_in[16];
  const float* mlp_b = (const float*)d_in[17];
  const float* tr_w = (const float*)d_in[18];
  const float* tr_b = (const float*)d_in[19];

  char* ws = (char*)d_ws;
  size_t off = 0;
  auto alloc = [&](size_t bytes) {
    void* p = ws + off;
    off += (bytes + 255) & ~(size_t)255;
    return p;
  };
  unsigned short* aw_bf = (unsigned short*)alloc((size_t)I * I * 2);
  unsigned short* Wat_bf = (unsigned short*)alloc((size_t)U * UI * 2);
  unsigned short* mw_bf = (unsigned short*)alloc((size_t)I * D * 2);
  unsigned short* h_bf = (unsigned short*)alloc((size_t)UI * I * 2);   // 48MB
  unsigned short* aT_bf = (unsigned short*)alloc((size_t)I * UI * 2);  // 48MB
  float* scores = (float*)alloc((size_t)U * I * 4);                    // 32MB
  unsigned short* at_bf = (unsigned short*)alloc((size_t)U * I * 2);
  unsigned short* x_bf[2];
  float* ue_f[2];
  float* ie_f[2];
  unsigned short* ieT[2];
  float* ueat_f[2];
  for (int b = 0; b < 2; b++) {
    x_bf[b] = (unsigned short*)alloc((size_t)UI * D * 2);
    ue_f[b] = (float*)alloc((size_t)U * D * 4);
    ie_f[b] = (float*)alloc((size_t)I * D * 4);
    ieT[b] = (unsigned short*)alloc((size_t)D * I * 2);
    ueat_f[b] = (float*)alloc((size_t)U * D * 4);
  }
  // Lifetime-based aliases:
  float* pue = (float*)h_bf;       // dead before h written
  float* pie = (float*)aT_bf;      // dead before aT written
  float* pueat = scores;           // clobbers scores AFTER softmax read them
  float* scores2 = (float*)h_bf;   // z=1 slab; h dead once aT is built
  const long zsf = (long)(scores2 - scores);

  const dim3 blk(256);

  // ue: [U,64] over K=I, both branches, KS=8
  k_sgemm64s<0, 0><<<dim3(U / 64, 8, 2), blk, 0, stream>>>(
      ui[0], ui[1], Wu[0], Wu[1], pue, I / 8, I, I, U);
  k_reduce<1, 1, 0><<<dim3(U * 64 / 256, 2), blk, 0, stream>>>(
      pue, (size_t)8 * U * 64, ue_f[0], ue_f[1], x_bf[0], x_bf[1], nullptr,
      nullptr, U, 8, 0);
  // ie: [I,64] over K=U (A = ui^T), both branches, KS=8
  k_sgemm64s<1, 0><<<dim3(I / 64, 8, 2), blk, 0, stream>>>(
      ui[0], ui[1], Wi[0], Wi[1], pie, U / 8, I, U, I);
  k_reduce<1, 1, 1><<<dim3(I * 64 / 256, 2), blk, 0, stream>>>(
      pie, (size_t)8 * I * 64, ie_f[0], ie_f[1], x_bf[0] + (size_t)U * D,
      x_bf[1] + (size_t)U * D, ieT[0], ieT[1], I, 8, I);

  for (int b = 0; b < 2; b++) {
    k_f32_to_bf16<<<2048, blk, 0, stream>>>(aw[b], aw_bf, (long)I * I);
    k_f32_to_bf16<<<2048, blk, 0, stream>>>(Wat[b], Wat_bf, (long)U * UI);
    k_f32_to_bf16<<<128, blk, 0, stream>>>(mw[b], mw_bf, (long)I * D);

    // h = tanh(relu(x @ mw^T + mb)) : [6144,4096], K=64
    k_gemm128<2><<<dim3(UI / 128, I / 128), blk, 0, stream>>>(
        x_bf[b], mw_bf, nullptr, h_bf, mb[b], UI, I, D);
    // aT = tanh(aw @ h^T + ab) : [4096,6144], K=4096
    k_gemm256<1><<<dim3(I / 256, UI / 256, 1), dim3(512), 0, stream>>>(
        aw_bf, h_bf, nullptr, aT_bf, ab[b], I, UI, I, I, 0);
    // scores = Wat @ a : [2048,4096], K=6144, split-K z=2
    k_gemm256<0><<<dim3(U / 256, I / 256, 2), dim3(512), 0, stream>>>(
        Wat_bf, aT_bf, scores, nullptr, nullptr, U, I, UI, UI / 2, zsf);
    // softmax over slab0+slab1
    k_softmax<<<U, blk, 0, stream>>>(scores, scores2, at_bf);
    // ue_at = at @ ie : [U,64] over K=I, KS=8 (per branch)
    k_sgemm64s<2, 2><<<dim3(U / 64, 8, 1), blk, 0, stream>>>(
        at_bf, at_bf, ieT[b], ieT[b], pueat, I / 8, I, I, U);
    k_reduce<1, 0, 0><<<dim3(U * 64 / 256, 1), blk, 0, stream>>>(
        pueat, 0, ueat_f[b], ueat_f[b], nullptr, nullptr, nullptr, nullptr, U,
        8, 0);
  }

  float* out_user = (float*)d_out;
  float* out_item = (float*)d_out + (size_t)U * D;
  k_user<<<U / 4, blk, 0, stream>>>(ue_f[0], ueat_f[0], ue_f[1], ueat_f[1],
                                    mlp_w, mlp_b, tr_w, tr_b, out_user);
  k_item<<<I / 4, blk, 0, stream>>>(ie_f[0], ie_f[1], mlp_w, mlp_b, out_item);
}

// Round 4
// 841.946 us; speedup vs baseline: 1.6069x; 1.0564x over previous
//
#include <hip/hip_runtime.h>
#include <stdint.h>
#include <math.h>

// ---------------------------------------------------------------------------
// PAAE layer, MI355X (gfx950). Round 4: aT GEMM redesigned.
//  - k_gemmAT: 256x384 tile (grid 16x16 = 256 blocks, no quantization tail),
//    32x32x16 MFMA (1014 FLOP/cyc/SIMD vs 844), 3-slot LDS ring (120 KiB),
//    counted vmcnt(5), both-sides chunk-XOR swizzle, setprio.
//  - k_gemm256 (256x256, 16x16x32) retained for scores (grid already 256).
// ---------------------------------------------------------------------------

typedef short short8 __attribute__((ext_vector_type(8)));
typedef unsigned short ushort8 __attribute__((ext_vector_type(8)));
typedef float f32x4 __attribute__((ext_vector_type(4)));
typedef float f32x16 __attribute__((ext_vector_type(16)));

#define DEVI static __device__ __forceinline__

DEVI unsigned short f2bf(float f) {  // RNE float -> bf16 bits
  uint32_t u = __builtin_bit_cast(uint32_t, f);
  return (unsigned short)((u + 0x7fffu + ((u >> 16) & 1u)) >> 16);
}
DEVI float sigmoidf_(float x) { return 1.0f / (1.0f + expf(-x)); }

DEVI void gld16(const void* g, void* l) {
  __builtin_amdgcn_global_load_lds(
      (const __attribute__((address_space(1))) unsigned int*)g,
      (__attribute__((address_space(3))) unsigned int*)l, 16, 0, 0);
}

// ---------------------------------------------------------------------------
__global__ __launch_bounds__(256) void k_f32_to_bf16(
    const float* __restrict__ s, unsigned short* __restrict__ d, long n) {
  long i0 = ((long)blockIdx.x * 256 + threadIdx.x) * 8;
  long stride = (long)gridDim.x * 256 * 8;
  for (long i = i0; i < n; i += stride) {
    f32x4 a = *(const f32x4*)(s + i);
    f32x4 b = *(const f32x4*)(s + i + 4);
    ushort8 o;
    o[0] = f2bf(a[0]); o[1] = f2bf(a[1]); o[2] = f2bf(a[2]); o[3] = f2bf(a[3]);
    o[4] = f2bf(b[0]); o[5] = f2bf(b[1]); o[6] = f2bf(b[2]); o[7] = f2bf(b[3]);
    *(ushort8*)(d + i) = o;
  }
}

// ---------------------------------------------------------------------------
// aT = tanh(A[M,K] * B[N,K]^T + bias[row]) : tile 256x384, 32x32x16 MFMA.
// LDS ring: 3 slots/operand, slot = [rows][32 k] bf16. A 3x16KB, B 3x24KB.
// Swizzle: 16B-chunk c stored at c ^ ((row>>1)&3) (via inverse-swizzled
// global source, linear LDS dest); reads XOR the same -> 32 banks/8 lanes.
// Requires M%256==0, N%384==0, K%32==0.
// ---------------------------------------------------------------------------
__global__ __launch_bounds__(512, 2) void k_gemmAT(
    const unsigned short* __restrict__ A, const unsigned short* __restrict__ B,
    unsigned short* __restrict__ outB, const float* __restrict__ bias, int M,
    int N, int K) {
  __shared__ unsigned short lds[61440];  // A: 3*8192 @0, B: 3*12288 @24576
  const int tid = threadIdx.x, lane = tid & 63;
  const int wid = tid >> 6, wr = wid >> 2, wc = wid & 3;
  const int bm = blockIdx.x * 256, bn = blockIdx.y * 384;
  const int NPH = K >> 5;

  const int R0 = tid >> 2, Q = tid & 3;  // staging row / 16B chunk
  const int qd = Q ^ ((R0 >> 1) & 3);    // inverse-swizzled source chunk
  const int r32 = lane & 31, hi = lane >> 5;
  const int rx = (r32 >> 1) & 3;         // read-side chunk XOR

  f32x16 acc[4][3] = {};

  auto stage = [&](int j) {
    const int slot = j % 3;
    const long kcol = (long)j << 5;
#pragma unroll
    for (int p = 0; p < 2; p++) {
      const int R = p * 128 + R0;
      gld16(A + (size_t)(bm + R) * K + kcol + qd * 8,
            &lds[slot * 8192 + R * 32 + Q * 8]);
    }
#pragma unroll
    for (int p = 0; p < 3; p++) {
      const int R = p * 128 + R0;
      gld16(B + (size_t)(bn + R) * K + kcol + qd * 8,
            &lds[24576 + slot * 12288 + R * 32 + Q * 8]);
    }
  };

  stage(0);
  stage(1);

  for (int g = 0; g < NPH; ++g) {
    // in-flight at this point: stage(g) [maybe] + stage(g+1) = up to 10 loads;
    // vmcnt(5) drains stage(g) -> slot g%3 complete for ALL waves after barrier.
    if (g + 1 < NPH)
      asm volatile("s_waitcnt vmcnt(5)\n\ts_barrier" ::: "memory");
    else
      asm volatile("s_waitcnt vmcnt(0)\n\ts_barrier" ::: "memory");

    const int slot = g % 3;
    const unsigned short* As = &lds[slot * 8192];
    const unsigned short* Bs = &lds[24576 + slot * 12288];

    // k-step 0 (k 0..15): chunk base = hi
    short8 a0[4], b0[3];
#pragma unroll
    for (int m = 0; m < 4; m++)
      a0[m] = *(const short8*)(As + (wr * 128 + m * 32 + r32) * 32 +
                               ((hi ^ rx) << 3));
#pragma unroll
    for (int n = 0; n < 3; n++)
      b0[n] = *(const short8*)(Bs + (wc * 96 + n * 32 + r32) * 32 +
                               ((hi ^ rx) << 3));

    if (g + 2 < NPH) stage(g + 2);  // targets slot (g-1)%3, freed last phase

    __builtin_amdgcn_s_setprio(1);
#pragma unroll
    for (int m = 0; m < 4; m++)
#pragma unroll
      for (int n = 0; n < 3; n++)
        acc[m][n] = __builtin_amdgcn_mfma_f32_32x32x16_bf16(a0[m], b0[n],
                                                            acc[m][n], 0, 0, 0);
    __builtin_amdgcn_s_setprio(0);

    // k-step 1 (k 16..31): chunk base = 2 + hi
    short8 a1[4], b1[3];
#pragma unroll
    for (int m = 0; m < 4; m++)
      a1[m] = *(const short8*)(As + (wr * 128 + m * 32 + r32) * 32 +
                               (((2 + hi) ^ rx) << 3));
#pragma unroll
    for (int n = 0; n < 3; n++)
      b1[n] = *(const short8*)(Bs + (wc * 96 + n * 32 + r32) * 32 +
                               (((2 + hi) ^ rx) << 3));

    __builtin_amdgcn_s_setprio(1);
#pragma unroll
    for (int m = 0; m < 4; m++)
#pragma unroll
      for (int n = 0; n < 3; n++)
        acc[m][n] = __builtin_amdgcn_mfma_f32_32x32x16_bf16(a1[m], b1[n],
                                                            acc[m][n], 0, 0, 0);
    __builtin_amdgcn_s_setprio(0);
  }

  // C/D 32x32 layout: col = lane&31, row = (r&3) + 8*(r>>2) + 4*(lane>>5)
#pragma unroll
  for (int m = 0; m < 4; m++) {
#pragma unroll
    for (int n = 0; n < 3; n++) {
      const int col = bn + wc * 96 + n * 32 + r32;
#pragma unroll
      for (int r = 0; r < 16; r++) {
        const int row = bm + wr * 128 + m * 32 + (r & 3) + 8 * (r >> 2) + 4 * hi;
        outB[(size_t)row * N + col] = f2bf(tanhf(acc[m][n][r] + bias[row]));
      }
    }
  }
}

// ---------------------------------------------------------------------------
// 256x256 pipelined bf16 GEMM (scores): C = A[M,K]*B[N,K]^T, split-K partial.
// outF[z*zsf + row*N + col] = acc
// ---------------------------------------------------------------------------
__global__ __launch_bounds__(512, 2) void k_gemm256(
    const unsigned short* __restrict__ A, const unsigned short* __restrict__ B,
    float* __restrict__ outF, int M, int N, int K, int kchunk, long zsf) {
  __shared__ unsigned short lds[65536];  // A slots [4][256][32] @0; B @32768
  const int tid = threadIdx.x, lane = tid & 63;
  const int wid = tid >> 6, wr = wid >> 2, wc = wid & 3;
  const int bm = blockIdx.x * 256, bn = blockIdx.y * 256;
  const int kz = blockIdx.z;
  const long kbase = (long)kz * kchunk;
  const int NPH = (kchunk / 64) * 2;

  const int R0 = tid >> 2, Q = tid & 3;
  const int qd = Q ^ ((R0 >> 1) & 3);
  const int q = lane >> 4, rl = lane & 15;
  const int qe = (q ^ ((rl >> 1) & 3)) << 3;

  f32x4 acc[8][4] = {};

  auto stage = [&](int j) {
    const int slot = j & 3;
    const long kcol = kbase + (long)(j >> 1) * 64 + (j & 1) * 32;
#pragma unroll
    for (int i = 0; i < 2; i++) {
      const int R = i * 128 + R0;
      gld16(A + (size_t)(bm + R) * K + kcol + qd * 8,
            &lds[slot * 8192 + R * 32 + Q * 8]);
      gld16(B + (size_t)(bn + R) * K + kcol + qd * 8,
            &lds[32768 + slot * 8192 + R * 32 + Q * 8]);
    }
  };

  for (int j = 0; j < 3 && j < NPH; ++j) stage(j);

  for (int g = 0; g < NPH; ++g) {
    if (g + 2 < NPH)
      asm volatile("s_waitcnt vmcnt(8)\n\ts_barrier" ::: "memory");
    else if (g + 1 < NPH)
      asm volatile("s_waitcnt vmcnt(4)\n\ts_barrier" ::: "memory");
    else
      asm volatile("s_waitcnt vmcnt(0)\n\ts_barrier" ::: "memory");

    const unsigned short* As = &lds[(g & 3) * 8192];
    const unsigned short* Bs = &lds[32768 + (g & 3) * 8192];
    short8 af[8], bfr[4];
#pragma unroll
    for (int m = 0; m < 8; m++)
      af[m] = *(const short8*)(As + (wr * 128 + m * 16 + rl) * 32 + qe);
#pragma unroll
    for (int n = 0; n < 4; n++)
      bfr[n] = *(const short8*)(Bs + (wc * 64 + n * 16 + rl) * 32 + qe);

    if (g + 3 < NPH) stage(g + 3);

    __builtin_amdgcn_s_setprio(1);
#pragma unroll
    for (int m = 0; m < 8; m++)
#pragma unroll
      for (int n = 0; n < 4; n++)
        acc[m][n] = __builtin_amdgcn_mfma_f32_16x16x32_bf16(af[m], bfr[n],
                                                            acc[m][n], 0, 0, 0);
    __builtin_amdgcn_s_setprio(0);
  }

#pragma unroll
  for (int m = 0; m < 8; m++) {
#pragma unroll
    for (int n = 0; n < 4; n++) {
      const int col = bn + wc * 64 + n * 16 + rl;
#pragma unroll
      for (int r = 0; r < 4; r++) {
        const int row = bm + wr * 128 + m * 16 + q * 4 + r;
        outF[(long)kz * zsf + (size_t)row * N + col] = acc[m][n][r];
      }
    }
  }
}

// ---------------------------------------------------------------------------
// 128x128 bf16 GEMM (for h, K=64), swizzled.
// EPI 2: outB = bf16(tanh(relu(acc + bias[col])))
// ---------------------------------------------------------------------------
template <int EPI>
__global__ __launch_bounds__(256) void k_gemm128(
    const unsigned short* __restrict__ A, const unsigned short* __restrict__ B,
    float* __restrict__ outF, unsigned short* __restrict__ outB,
    const float* __restrict__ bias, int M, int N, int K) {
  __shared__ unsigned short As[128 * 32];
  __shared__ unsigned short Bs[128 * 32];
  const int tid = threadIdx.x, lane = tid & 63, wid = tid >> 6;
  const int wr = wid >> 1, wc = wid & 1;
  const int bm = blockIdx.x * 128, bn = blockIdx.y * 128;
  const int c0 = tid, c1 = tid + 256;
  const int s0 = ((c0 & 3) ^ ((c0 >> 3) & 3)) << 3;
  const int s1 = ((c1 & 3) ^ ((c1 >> 3) & 3)) << 3;
  const int rl = lane & 15, q = lane >> 4;
  const int qe = (q ^ ((rl >> 1) & 3)) << 3;

  f32x4 acc[4][4] = {};

  for (int k0 = 0; k0 < K; k0 += 32) {
    gld16(A + (size_t)(bm + (c0 >> 2)) * K + k0 + s0, As + c0 * 8);
    gld16(A + (size_t)(bm + (c1 >> 2)) * K + k0 + s1, As + c1 * 8);
    gld16(B + (size_t)(bn + (c0 >> 2)) * K + k0 + s0, Bs + c0 * 8);
    gld16(B + (size_t)(bn + (c1 >> 2)) * K + k0 + s1, Bs + c1 * 8);
    __syncthreads();

    short8 af[4], bfr[4];
#pragma unroll
    for (int mi = 0; mi < 4; mi++)
      af[mi] = *(const short8*)(As + (wr * 64 + mi * 16 + rl) * 32 + qe);
#pragma unroll
    for (int ni = 0; ni < 4; ni++)
      bfr[ni] = *(const short8*)(Bs + (wc * 64 + ni * 16 + rl) * 32 + qe);
#pragma unroll
    for (int mi = 0; mi < 4; mi++)
#pragma unroll
      for (int ni = 0; ni < 4; ni++)
        acc[mi][ni] = __builtin_amdgcn_mfma_f32_16x16x32_bf16(
            af[mi], bfr[ni], acc[mi][ni], 0, 0, 0);
    __syncthreads();
  }

#pragma unroll
  for (int mi = 0; mi < 4; mi++) {
#pragma unroll
    for (int ni = 0; ni < 4; ni++) {
      const int col = bn + wc * 64 + ni * 16 + rl;
#pragma unroll
      for (int r = 0; r < 4; r++) {
        const int row = bm + wr * 64 + mi * 16 + q * 4 + r;
        const float v = acc[mi][ni][r];
        if (EPI == 0) {
          outF[(size_t)row * N + col] = v;
        } else if (EPI == 1) {
          outB[(size_t)row * N + col] = f2bf(tanhf(v + bias[row]));
        } else {
          outB[(size_t)row * N + col] = f2bf(tanhf(fmaxf(v + bias[col], 0.0f)));
        }
      }
    }
  }
}

// ---------------------------------------------------------------------------
// Skinny GEMM, N=64, split-K. grid: (M/64, KS, nbr)
// ---------------------------------------------------------------------------
template <int AMODE, int BMODE>
__global__ __launch_bounds__(256) void k_sgemm64s(
    const void* __restrict__ A0, const void* __restrict__ A1,
    const void* __restrict__ B0, const void* __restrict__ B1,
    float* __restrict__ P, int kchunk, int lda, int ldb, int M) {
  const int br = blockIdx.z, kz = blockIdx.y, KS = gridDim.y;
  const void* Av = br ? A1 : A0;
  const void* Bv = br ? B1 : B0;

  __shared__ unsigned short As[64 * 40];
  __shared__ unsigned short Bs[64 * 40];
  const int tid = threadIdx.x, lane = tid & 63, w = tid >> 6;
  const int tm = blockIdx.x * 64;

  f32x4 acc[4] = {};
  const int kbeg = kz * kchunk, kend = kbeg + kchunk;

  for (int k0 = kbeg; k0 < kend; k0 += 32) {
    if (AMODE == 0) {
      const float* Af = (const float*)Av;
      const int m = tid >> 2, k8 = (tid & 3) << 3;
      f32x4 x0 = *(const f32x4*)(Af + (size_t)(tm + m) * lda + k0 + k8);
      f32x4 x1 = *(const f32x4*)(Af + (size_t)(tm + m) * lda + k0 + k8 + 4);
      ushort8 o;
      o[0] = f2bf(x0[0]); o[1] = f2bf(x0[1]); o[2] = f2bf(x0[2]); o[3] = f2bf(x0[3]);
      o[4] = f2bf(x1[0]); o[5] = f2bf(x1[1]); o[6] = f2bf(x1[2]); o[7] = f2bf(x1[3]);
      *(ushort8*)(As + m * 40 + k8) = o;
    } else if (AMODE == 1) {
      const float* Af = (const float*)Av;
#pragma unroll
      for (int t = 0; t < 2; t++) {
        const int c = tid + t * 256;
        const int u = c >> 4, i4 = (c & 15) << 2;
        f32x4 x = *(const f32x4*)(Af + (size_t)(k0 + u) * lda + tm + i4);
        As[(i4 + 0) * 40 + u] = f2bf(x[0]);
        As[(i4 + 1) * 40 + u] = f2bf(x[1]);
        As[(i4 + 2) * 40 + u] = f2bf(x[2]);
        As[(i4 + 3) * 40 + u] = f2bf(x[3]);
      }
    } else {
      const unsigned short* Ab = (const unsigned short*)Av;
      const int m = tid >> 2, k8 = (tid & 3) << 3;
      *(ushort8*)(As + m * 40 + k8) =
          *(const ushort8*)(Ab + (size_t)(tm + m) * lda + k0 + k8);
    }
    if (BMODE == 0) {
      const float* Bf = (const float*)Bv;
      const int n = tid >> 2, k8 = (tid & 3) << 3;
      f32x4 x0 = *(const f32x4*)(Bf + (size_t)n * ldb + k0 + k8);
      f32x4 x1 = *(const f32x4*)(Bf + (size_t)n * ldb + k0 + k8 + 4);
      ushort8 o;
      o[0] = f2bf(x0[0]); o[1] = f2bf(x0[1]); o[2] = f2bf(x0[2]); o[3] = f2bf(x0[3]);
      o[4] = f2bf(x1[0]); o[5] = f2bf(x1[1]); o[6] = f2bf(x1[2]); o[7] = f2bf(x1[3]);
      *(ushort8*)(Bs + n * 40 + k8) = o;
    } else {
      const unsigned short* Bb = (const unsigned short*)Bv;
      const int n = tid >> 2, k8 = (tid & 3) << 3;
      *(ushort8*)(Bs + n * 40 + k8) =
          *(const ushort8*)(Bb + (size_t)n * ldb + k0 + k8);
    }
    __syncthreads();

    const int kr = (lane >> 4) << 3;
    short8 a = *(const short8*)(As + (w * 16 + (lane & 15)) * 40 + kr);
#pragma unroll
    for (int ni = 0; ni < 4; ni++) {
      short8 bb = *(const short8*)(Bs + (ni * 16 + (lane & 15)) * 40 + kr);
      acc[ni] = __builtin_amdgcn_mfma_f32_16x16x32_bf16(a, bb, acc[ni], 0, 0, 0);
    }
    __syncthreads();
  }

  float* out = P + ((size_t)(br * KS + kz) * M) * 64;
#pragma unroll
  for (int ni = 0; ni < 4; ni++) {
    const int col = ni * 16 + (lane & 15);
#pragma unroll
    for (int r = 0; r < 4; r++) {
      const int row = tm + w * 16 + ((lane >> 4) << 2) + r;
      out[(size_t)row * 64 + col] = acc[ni][r];
    }
  }
}

// ---------------------------------------------------------------------------
template <int WF, int WB, int WT>
__global__ __launch_bounds__(256) void k_reduce(
    const float* __restrict__ P, size_t pbr_stride, float* F0, float* F1,
    unsigned short* Bo0, unsigned short* Bo1, unsigned short* T0,
    unsigned short* T1, int M, int KS, int ldT) {
  const int br = blockIdx.y;
  const float* Pp = P + (size_t)br * pbr_stride;
  const size_t i = (size_t)blockIdx.x * 256 + threadIdx.x;
  const size_t n = (size_t)M * 64;
  float s = 0.f;
  for (int k = 0; k < KS; k++) s += Pp[(size_t)k * n + i];
  if (WF) (br ? F1 : F0)[i] = s;
  if (WB) (br ? Bo1 : Bo0)[i] = f2bf(s);
  if (WT) {
    const int row = (int)(i >> 6), col = (int)(i & 63);
    (br ? T1 : T0)[(size_t)col * ldT + row] = f2bf(s);
  }
}

// ---------------------------------------------------------------------------
__global__ __launch_bounds__(256) void k_softmax(
    const float* __restrict__ S0, const float* __restrict__ S1,
    unsigned short* __restrict__ Pout) {
  const int row = blockIdx.x, tid = threadIdx.x;
  const float* s0 = S0 + (size_t)row * 4096;
  const float* s1 = S1 + (size_t)row * 4096;
  float v[16];
  float m = -1e30f;
#pragma unroll
  for (int j = 0; j < 16; j++) {
    v[j] = s0[tid + j * 256] + s1[tid + j * 256];
    m = fmaxf(m, v[j]);
  }
  __shared__ float red[4], red2[4];
  for (int o = 32; o; o >>= 1) m = fmaxf(m, __shfl_down(m, o));
  if ((tid & 63) == 0) red[tid >> 6] = m;
  __syncthreads();
  m = fmaxf(fmaxf(red[0], red[1]), fmaxf(red[2], red[3]));
  float sum = 0.0f;
#pragma unroll
  for (int j = 0; j < 16; j++) {
    v[j] = expf(v[j] - m);
    sum += v[j];
  }
  for (int o = 32; o; o >>= 1) sum += __shfl_down(sum, o);
  if ((tid & 63) == 0) red2[tid >> 6] = sum;
  __syncthreads();
  const float inv = 1.0f / (red2[0] + red2[1] + red2[2] + red2[3]);
  unsigned short* p = Pout + (size_t)row * 4096;
#pragma unroll
  for (int j = 0; j < 16; j++) p[tid + j * 256] = f2bf(v[j] * inv);
}

// ---------------------------------------------------------------------------
__global__ __launch_bounds__(256) void k_user(
    const float* __restrict__ ue_mp, const float* __restrict__ ueat_mp,
    const float* __restrict__ ue_pmp, const float* __restrict__ ueat_pmp,
    const float* __restrict__ mlp_w, const float* __restrict__ mlp_b,
    const float* __restrict__ tr_w, const float* __restrict__ tr_b,
    float* __restrict__ out) {
  const int tid = threadIdx.x, d = tid & 63, w = tid >> 6;
  const int m = blockIdx.x * 4 + w;
  __shared__ float fus[4][64];
  float a1 = mlp_b[d], a2 = a1;
  const float* r1 = ue_mp + (size_t)m * 64;
  const float* r2 = ueat_mp + (size_t)m * 64;
  const float* r3 = ue_pmp + (size_t)m * 64;
  const float* r4 = ueat_pmp + (size_t)m * 64;
  const float* w1 = mlp_w + (size_t)d * 128;
#pragma unroll 8
  for (int k = 0; k < 64; k++) {
    const float wv = w1[k];
    a1 += r1[k] * wv;
    a2 += r3[k] * wv;
  }
#pragma unroll 8
  for (int k = 0; k < 64; k++) {
    const float wv = w1[64 + k];
    a1 += r2[k] * wv;
    a2 += r4[k] * wv;
  }
  const float u1 = sigmoidf_(a1), u2 = sigmoidf_(a2);
  const float rate = sigmoidf_(u1 + u2);
  fus[w][d] = rate * u1 + (1.0f - rate) * u2;
  __syncthreads();
  float o = tr_b[d];
  const float* tw = tr_w + (size_t)d * 64;
#pragma unroll 8
  for (int k = 0; k < 64; k++) o += fus[w][k] * tw[k];
  out[(size_t)m * 64 + d] = tanhf(o);
}

__global__ __launch_bounds__(256) void k_item(
    const float* __restrict__ ie_mp, const float* __restrict__ ie_pmp,
    const float* __restrict__ mlp_w, const float* __restrict__ mlp_b,
    float* __restrict__ out) {
  const int tid = threadIdx.x, d = tid & 63, w = tid >> 6;
  const int i = blockIdx.x * 4 + w;
  float a = mlp_b[d];
  const float* r1 = ie_mp + (size_t)i * 64;
  const float* r2 = ie_pmp + (size_t)i * 64;
  const float* wp = mlp_w + (size_t)d * 128;
#pragma unroll 8
  for (int k = 0; k < 64; k++) {
    a += r1[k] * wp[k];
    a += r2[k] * wp[64 + k];
  }
  out[(size_t)i * 64 + d] = sigmoidf_(a);
}

// ---------------------------------------------------------------------------
extern "C" void kernel_launch(void* const* d_in, const int* in_sizes, int n_in,
                              void* d_out, int out_size, void* d_ws,
                              size_t ws_size, hipStream_t stream) {
  const int U = 2048, I = 4096, D = 64, UI = 6144;

  const float* ui[2] = {(const float*)d_in[0], (const float*)d_in[1]};
  const float* Wu[2] = {(const float*)d_in[2], (const float*)d_in[3]};
  const float* Wi[2] = {(const float*)d_in[4], (const float*)d_in[5]};
  const float* mw[2] = {(const float*)d_in[6], (const float*)d_in[11]};
  const float* mb[2] = {(const float*)d_in[7], (const float*)d_in[12]};
  const float* aw[2] = {(const float*)d_in[8], (const float*)d_in[13]};
  const float* ab[2] = {(const float*)d_in[9], (const float*)d_in[14]};
  const float* Wat[2] = {(const float*)d_in[10], (const float*)d_in[15]};
  const float* mlp_w = (const float*)d_in[16];
  const float* mlp_b = (const float*)d_in[17];
  const float* tr_w = (const float*)d_in[18];
  const float* tr_b = (const float*)d_in[19];

  char* ws = (char*)d_ws;
  size_t off = 0;
  auto alloc = [&](size_t bytes) {
    void* p = ws + off;
    off += (bytes + 255) & ~(size_t)255;
    return p;
  };
  unsigned short* aw_bf = (unsigned short*)alloc((size_t)I * I * 2);
  unsigned short* Wat_bf = (unsigned short*)alloc((size_t)U * UI * 2);
  unsigned short* mw_bf = (unsigned short*)alloc((size_t)I * D * 2);
  unsigned short* h_bf = (unsigned short*)alloc((size_t)UI * I * 2);   // 48MB
  unsigned short* aT_bf = (unsigned short*)alloc((size_t)I * UI * 2);  // 48MB
  float* scores = (float*)alloc((size_t)U * I * 4);                    // 32MB
  unsigned short* at_bf = (unsigned short*)alloc((size_t)U * I * 2);
  unsigned short* x_bf[2];
  float* ue_f[2];
  float* ie_f[2];
  unsigned short* ieT[2];
  float* ueat_f[2];
  for (int b = 0; b < 2; b++) {
    x_bf[b] = (unsigned short*)alloc((size_t)UI * D * 2);
    ue_f[b] = (float*)alloc((size_t)U * D * 4);
    ie_f[b] = (float*)alloc((size_t)I * D * 4);
    ieT[b] = (unsigned short*)alloc((size_t)D * I * 2);
    ueat_f[b] = (float*)alloc((size_t)U * D * 4);
  }
  // Lifetime-based aliases:
  float* pue = (float*)h_bf;       // dead before h written
  float* pie = (float*)aT_bf;      // dead before aT written
  float* pueat = scores;           // clobbers scores AFTER softmax read them
  float* scores2 = (float*)h_bf;   // z=1 slab; h dead once aT is built
  const long zsf = (long)(scores2 - scores);

  const dim3 blk(256);

  // ue: [U,64] over K=I, both branches, KS=8
  k_sgemm64s<0, 0><<<dim3(U / 64, 8, 2), blk, 0, stream>>>(
      ui[0], ui[1], Wu[0], Wu[1], pue, I / 8, I, I, U);
  k_reduce<1, 1, 0><<<dim3(U * 64 / 256, 2), blk, 0, stream>>>(
      pue, (size_t)8 * U * 64, ue_f[0], ue_f[1], x_bf[0], x_bf[1], nullptr,
      nullptr, U, 8, 0);
  // ie: [I,64] over K=U (A = ui^T), both branches, KS=8
  k_sgemm64s<1, 0><<<dim3(I / 64, 8, 2), blk, 0, stream>>>(
      ui[0], ui[1], Wi[0], Wi[1], pie, U / 8, I, U, I);
  k_reduce<1, 1, 1><<<dim3(I * 64 / 256, 2), blk, 0, stream>>>(
      pie, (size_t)8 * I * 64, ie_f[0], ie_f[1], x_bf[0] + (size_t)U * D,
      x_bf[1] + (size_t)U * D, ieT[0], ieT[1], I, 8, I);

  for (int b = 0; b < 2; b++) {
    k_f32_to_bf16<<<2048, blk, 0, stream>>>(aw[b], aw_bf, (long)I * I);
    k_f32_to_bf16<<<2048, blk, 0, stream>>>(Wat[b], Wat_bf, (long)U * UI);
    k_f32_to_bf16<<<128, blk, 0, stream>>>(mw[b], mw_bf, (long)I * D);

    // h = tanh(relu(x @ mw^T + mb)) : [6144,4096], K=64
    k_gemm128<2><<<dim3(UI / 128, I / 128), blk, 0, stream>>>(
        x_bf[b], mw_bf, nullptr, h_bf, mb[b], UI, I, D);
    // aT = tanh(aw @ h^T + ab) : [4096,6144], K=4096 ; grid 16x16 = 256
    k_gemmAT<<<dim3(I / 256, UI / 384), dim3(512), 0, stream>>>(
        aw_bf, h_bf, aT_bf, ab[b], I, UI, I);
    // scores = Wat @ a : [2048,4096], K=6144, split-K z=2 ; grid 256
    k_gemm256<<<dim3(U / 256, I / 256, 2), dim3(512), 0, stream>>>(
        Wat_bf, aT_bf, scores, U, I, UI, UI / 2, zsf);
    // softmax over slab0+slab1
    k_softmax<<<U, blk, 0, stream>>>(scores, scores2, at_bf);
    // ue_at = at @ ie : [U,64] over K=I, KS=8 (per branch)
    k_sgemm64s<2, 2><<<dim3(U / 64, 8, 1), blk, 0, stream>>>(
        at_bf, at_bf, ieT[b], ieT[b], pueat, I / 8, I, I, U);
    k_reduce<1, 0, 0><<<dim3(U * 64 / 256, 1), blk, 0, stream>>>(
        pueat, 0, ueat_f[b], ueat_f[b], nullptr, nullptr, nullptr, nullptr, U,
        8, 0);
  }

  float* out_user = (float*)d_out;
  float* out_item = (float*)d_out + (size_t)U * D;
  k_user<<<U / 4, blk, 0, stream>>>(ue_f[0], ueat_f[0], ue_f[1], ueat_f[1],
                                    mlp_w, mlp_b, tr_w, tr_b, out_user);
  k_item<<<I / 4, blk, 0, stream>>>(ie_f[0], ie_f[1], mlp_w, mlp_b, out_item);
}